// Round 11
// baseline (929.834 us; speedup 1.0000x reference)
//
#include <hip/hip_runtime.h>
#include <hip/hip_bf16.h>

#define D_MODEL 2048
#define N_HEADS 16
#define HEAD_DIM 128
#define D_FF 8192
#define BATCH 2
#define SEQ 2048
#define M_TOK (BATCH * SEQ)
#define QKV_LD 6144
// 1/sqrt(128) * log2(e): folded into Wq/bq so scores are in exp2 domain
#define QSCALE 0.12751744f

typedef __attribute__((ext_vector_type(8))) short short8;
typedef __attribute__((ext_vector_type(4))) short short4v;
typedef __attribute__((ext_vector_type(4))) float f32x4;
typedef __attribute__((ext_vector_type(16))) float f32x16;
typedef __attribute__((ext_vector_type(2))) unsigned int uint2v;
typedef __attribute__((ext_vector_type(4))) unsigned int uint4v;

__device__ __forceinline__ unsigned short f2b(float f) {
  __hip_bfloat16 h = __float2bfloat16(f);
  return *reinterpret_cast<unsigned short*>(&h);
}
__device__ __forceinline__ float b2f(unsigned short u) {
  unsigned int x = ((unsigned int)u) << 16;
  return __uint_as_float(x);
}

__device__ __forceinline__ void gload_lds16(const void* gsrc, void* ldst) {
  __builtin_amdgcn_global_load_lds(
      (const __attribute__((address_space(1))) void*)gsrc,
      (__attribute__((address_space(3))) void*)ldst, 16, 0, 0);
}

__device__ __forceinline__ f32x16 mfma32(short8 a, short8 b, f32x16 c) {
  return __builtin_amdgcn_mfma_f32_32x32x16_bf16(a, b, c, 0, 0, 0);
}
__device__ __forceinline__ unsigned int cvtpk(float lo, float hi) {
  unsigned int r;
  asm("v_cvt_pk_bf16_f32 %0, %1, %2" : "=v"(r) : "v"(lo), "v"(hi));
  return r;
}
__device__ __forceinline__ uint2v plswap(unsigned int a, unsigned int b) {
  return __builtin_amdgcn_permlane32_swap(a, b, false, false);
}

// ---------------- f32 -> bf16 convert (optional scale) -----------------------
__global__ __launch_bounds__(256)
void cvt_kernel(const float* __restrict__ src, unsigned short* __restrict__ dst,
                int nchunks, float scale) {
  int i = blockIdx.x * blockDim.x + threadIdx.x;
  int stride = gridDim.x * blockDim.x;
  for (int c = i; c < nchunks; c += stride) {
    const float4 a = *(const float4*)(src + (size_t)c * 8);
    const float4 b = *(const float4*)(src + (size_t)c * 8 + 4);
    short8 r;
    r[0] = f2b(a.x * scale); r[1] = f2b(a.y * scale);
    r[2] = f2b(a.z * scale); r[3] = f2b(a.w * scale);
    r[4] = f2b(b.x * scale); r[5] = f2b(b.y * scale);
    r[6] = f2b(b.z * scale); r[7] = f2b(b.w * scale);
    *(short8*)(dst + (size_t)c * 8) = r;
  }
}

// ---------------- W1 -> bf16 with row interleave -----------------------------
// dst row r' = [b = r'>>6][half = (r'>>5)&1][r'&31] <- src row half*8192+b*32+(r'&31)
__global__ __launch_bounds__(256)
void cvt_w1p_kernel(const float* __restrict__ src,
                    unsigned short* __restrict__ dst) {
  int i = blockIdx.x * blockDim.x + threadIdx.x;
  int stride = gridDim.x * blockDim.x;
  const int total = 2 * D_FF * (D_MODEL / 8);
  for (int c = i; c < total; c += stride) {
    int rp = c >> 8, col8 = c & 255;
    int b = rp >> 6, half = (rp >> 5) & 1;
    int rs = half * D_FF + b * 32 + (rp & 31);
    const float* s = src + (size_t)rs * D_MODEL + col8 * 8;
    const float4 a = *(const float4*)s;
    const float4 bb = *(const float4*)(s + 4);
    short8 r;
    r[0] = f2b(a.x); r[1] = f2b(a.y); r[2] = f2b(a.z); r[3] = f2b(a.w);
    r[4] = f2b(bb.x); r[5] = f2b(bb.y); r[6] = f2b(bb.z); r[7] = f2b(bb.w);
    *(short8*)(dst + (size_t)c * 8) = r;
  }
}

// ---------------- b1 permuted to match W1' row order -------------------------
__global__ void permb1_kernel(const float* __restrict__ b1,
                              float* __restrict__ b1p) {
  int i = blockIdx.x * 256 + threadIdx.x;
  int b = i >> 6, half = (i >> 5) & 1;
  b1p[i] = b1[half * D_FF + b * 32 + (i & 31)];
}

// ---------------- concat bias: [(bq+rot)*QSCALE | bk | bv] -------------------
__global__ void biasqkv_kernel(const float* __restrict__ bq,
                               const float* __restrict__ bk,
                               const float* __restrict__ bv,
                               const float* __restrict__ rot,
                               float* __restrict__ outp) {
  int i = blockIdx.x * 256 + threadIdx.x;
  float v;
  if (i < 2048) v = (bq[i] + rot[i & (HEAD_DIM - 1)]) * QSCALE;
  else if (i < 4096) v = bk[i - 2048];
  else v = bv[i - 4096];
  outp[i] = v;
}

// ---------------- RMSNorm: f32 in -> bf16 out --------------------------------
__global__ __launch_bounds__(256)
void rmsnorm_kernel(const float* __restrict__ x, const float* __restrict__ wv,
                    unsigned short* __restrict__ outp) {
  const int row = blockIdx.x;
  const float* xr = x + (size_t)row * D_MODEL;
  const int base = threadIdx.x * 8;
  float4 a = *(const float4*)(xr + base);
  float4 c = *(const float4*)(xr + base + 4);
  float ss = a.x * a.x + a.y * a.y + a.z * a.z + a.w * a.w +
             c.x * c.x + c.y * c.y + c.z * c.z + c.w * c.w;
#pragma unroll
  for (int m = 1; m < 64; m <<= 1) ss += __shfl_xor(ss, m);
  __shared__ float red[4];
  if ((threadIdx.x & 63) == 0) red[threadIdx.x >> 6] = ss;
  __syncthreads();
  float tot = red[0] + red[1] + red[2] + red[3];
  float sc = rsqrtf(tot * (1.0f / D_MODEL) + 1e-8f);
  float4 w0 = *(const float4*)(wv + base);
  float4 w1 = *(const float4*)(wv + base + 4);
  short8 r;
  r[0] = f2b(a.x * sc * w0.x); r[1] = f2b(a.y * sc * w0.y);
  r[2] = f2b(a.z * sc * w0.z); r[3] = f2b(a.w * sc * w0.w);
  r[4] = f2b(c.x * sc * w1.x); r[5] = f2b(c.y * sc * w1.y);
  r[6] = f2b(c.z * sc * w1.z); r[7] = f2b(c.w * sc * w1.w);
  *(short8*)(outp + (size_t)row * D_MODEL + base) = r;
}

// ===== GEMM 256x256, BK=64, 2-phase/K-tile pipelined, 32x32x16 MFMA ==========
// Grid: (x = M-tiles, y = N-tiles) — consecutive block ids share the B panel
// (the large streamed operand) for L2/L3 locality.
// Swizzle: r8-proven (row&7)<<4 applied via pre-swizzled global source at
// staging + same XOR on reads (rule 21 both-sides).
// Phase p of a K-tile reads A-half p (sub-blocks 2p, 2p+1); B cached in regs
// from phase 0; 16 MFMA_32x32x16 per barrier window; vmcnt(4) once per K-tile.
// MODE 0: bf16 out + bias.  MODE 2: f32 partial out.  MODE 3: swiglu-fused
// bf16 out (W1': rows interleaved so cb0 = x1, cb1 = x2; out LD = N/2).
template <int MODE>
__global__ __launch_bounds__(512, 2)
void gemm_p8(const unsigned short* __restrict__ A, int lda,
             const unsigned short* __restrict__ W, int ldw,
             const float* __restrict__ bias, void* __restrict__ outp,
             int N, int K, size_t out_zstride) {
  __shared__ unsigned short AL[2][2][128 * 64];
  __shared__ unsigned short BL[2][2][128 * 64];
  const int t = threadIdx.x;
  const int l = t & 63, w = t >> 6;
  const int wm = w >> 2, wn = w & 3;
  const int ln = l & 31, hi = l >> 5;
  const int m0 = blockIdx.x << 8, n0 = blockIdx.y << 8;  // swapped roles
  const int koff = blockIdx.z * K;

  // staging: half-tile = 128 rows x 64 k; thread t stages chunks t, t+512
  const int r0 = t >> 3;
  const int cb16 = (t & 7) * 16;
  const int sel = ((cb16 ^ ((r0 & 7) << 4)) >> 1);  // r8 swizzle
  const unsigned short* Abase = A + (size_t)m0 * lda + koff;
  const unsigned short* Wbase = W + (size_t)n0 * ldw + koff;
  const int d0e = t * 8, d1e = (t + 512) * 8;

#define STAGE(XL, Xb, ld, dd, h, ktd)                                        \
  do {                                                                       \
    const unsigned short* s_ =                                               \
        (Xb) + (size_t)((h) * 128 + r0) * (ld) + (ktd) * 64 + sel;           \
    gload_lds16(s_, &XL[dd][h][d0e]);                                        \
    gload_lds16(s_ + (size_t)64 * (ld), &XL[dd][h][d1e]);                    \
  } while (0)

  const int swz = (ln & 7) << 4;                // r8 swizzle for all reads
  const int hb = wn >> 1;                       // B half for this wave
  const int browb = ((wn & 1) * 64 + ln) * 128; // B row base byte

  f32x16 acc[4][2] = {};
  short8 bf[2][4];  // B-frags held across both phases of a K-tile

#define READB(dd)                                                            \
  do {                                                                       \
    const char* Bb_ = (const char*)&BL[dd][hb][0];                           \
    _Pragma("unroll") for (int cb_ = 0; cb_ < 2; cb_++)                      \
      _Pragma("unroll") for (int ks_ = 0; ks_ < 4; ks_++)                    \
        bf[cb_][ks_] = *(const short8*)(Bb_ + browb + cb_ * 4096 +           \
                                        ((ks_ * 32 + hi * 16) ^ swz));       \
  } while (0)

// PHASE2(dd, p): reads A-half p (sub-blocks 2p, 2p+1), 16 MFMA.
#define PHASE2(dd, p, STAGE_STMT, VM_STMT)                                   \
  do {                                                                       \
    const char* Ab_ = (const char*)&AL[dd][p][0];                            \
    short8 af_[2][4];                                                        \
    if ((p) == 0) READB(dd);                                                 \
    _Pragma("unroll") for (int sb_ = 0; sb_ < 2; sb_++) {                    \
      _Pragma("unroll") for (int ks_ = 0; ks_ < 4; ks_++)                    \
        af_[sb_][ks_] = *(const short8*)(Ab_ +                               \
                                         (wm * 64 + sb_ * 32 + ln) * 128 +   \
                                         ((ks_ * 32 + hi * 16) ^ swz));      \
    }                                                                        \
    STAGE_STMT;                                                              \
    __builtin_amdgcn_sched_barrier(0);                                       \
    VM_STMT;                                                                 \
    __builtin_amdgcn_sched_barrier(0);                                       \
    __builtin_amdgcn_s_barrier();                                            \
    __builtin_amdgcn_sched_barrier(0);                                       \
    __builtin_amdgcn_s_setprio(1);                                           \
    _Pragma("unroll") for (int sb_ = 0; sb_ < 2; sb_++)                      \
      _Pragma("unroll") for (int cb_ = 0; cb_ < 2; cb_++)                    \
        _Pragma("unroll") for (int ks_ = 0; ks_ < 4; ks_++)                  \
          acc[2 * (p) + sb_][cb_] =                                          \
              mfma32(af_[sb_][ks_], bf[cb_][ks_], acc[2 * (p) + sb_][cb_]);  \
    __builtin_amdgcn_s_setprio(0);                                           \
    __builtin_amdgcn_sched_barrier(0);                                       \
    __builtin_amdgcn_s_barrier();                                            \
    __builtin_amdgcn_sched_barrier(0);                                       \
  } while (0)

  const int NT = K >> 6;

  // prologue: kt0 fully, kt1's A-half0 + B-half0 (proven r5-r10 chain)
  STAGE(AL, Abase, lda, 0, 0, 0);
  STAGE(AL, Abase, lda, 0, 1, 0);
  STAGE(BL, Wbase, ldw, 0, 0, 0);
  STAGE(BL, Wbase, ldw, 0, 1, 0);
  STAGE(AL, Abase, lda, 1, 0, 1);
  STAGE(BL, Wbase, ldw, 1, 0, 1);
  asm volatile("s_waitcnt vmcnt(4)" ::: "memory");
  __builtin_amdgcn_sched_barrier(0);
  __builtin_amdgcn_s_barrier();
  __builtin_amdgcn_sched_barrier(0);

  for (int kt = 0; kt < NT; kt += 2) {
    // ---- K-tile kt (dbuf 0) ----
    PHASE2(0, 0,
           {
             if (kt + 1 < NT) {
               STAGE(BL, Wbase, ldw, 1, 1, kt + 1);
               STAGE(AL, Abase, lda, 1, 1, kt + 1);
             }
           },
           {});
    PHASE2(0, 1,
           {
             if (kt + 2 < NT) {
               STAGE(AL, Abase, lda, 0, 0, kt + 2);
               STAGE(BL, Wbase, ldw, 0, 0, kt + 2);
             }
           },
           {
             if (kt + 2 < NT)
               asm volatile("s_waitcnt vmcnt(4)" ::: "memory");
             else
               asm volatile("s_waitcnt vmcnt(0)" ::: "memory");
           });
    // ---- K-tile kt+1 (dbuf 1) ----
    PHASE2(1, 0,
           {
             if (kt + 2 < NT) {
               STAGE(BL, Wbase, ldw, 0, 1, kt + 2);
               STAGE(AL, Abase, lda, 0, 1, kt + 2);
             }
           },
           {});
    PHASE2(1, 1,
           {
             if (kt + 3 < NT) {
               STAGE(AL, Abase, lda, 1, 0, kt + 3);
               STAGE(BL, Wbase, ldw, 1, 0, kt + 3);
             }
           },
           {
             if (kt + 3 < NT)
               asm volatile("s_waitcnt vmcnt(4)" ::: "memory");
             else
               asm volatile("s_waitcnt vmcnt(0)" ::: "memory");
           });
  }
#undef PHASE2
#undef READB
#undef STAGE

  // epilogue: row = m0+(rb>>1)*128+wm*64+(rb&1)*32+(r&3)+8*(r>>2)+4*hi
#pragma unroll
  for (int rb = 0; rb < 4; rb++) {
    const int rowb = m0 + (rb >> 1) * 128 + wm * 64 + (rb & 1) * 32 + 4 * hi;
    if (MODE == 3) {
      const int col0 = n0 + wn * 64 + ln;
      const float b1v = bias[col0];
      const float b2v = bias[col0 + 32];
      const int jout = (n0 >> 1) + wn * 32 + ln;
#pragma unroll
      for (int r = 0; r < 16; r++) {
        const int row = rowb + (r & 3) + 8 * (r >> 2);
        float x1 = acc[rb][0][r] + b1v;
        float x2 = acc[rb][1][r] + b2v;
        float sg = x2 / (1.0f + __expf(-x2));
        ((unsigned short*)outp)[(size_t)row * (N >> 1) + jout] = f2b(x1 * sg);
      }
    } else {
#pragma unroll
      for (int cb = 0; cb < 2; cb++) {
        const int col = n0 + wn * 64 + cb * 32 + ln;
        const float bv = (MODE == 0) ? bias[col] : 0.0f;
#pragma unroll
        for (int r = 0; r < 16; r++) {
          const int row = rowb + (r & 3) + 8 * (r >> 2);
          const float vv = acc[rb][cb][r] + bv;
          if (MODE == 0)
            ((unsigned short*)outp)[(size_t)row * N + col] = f2b(vv);
          else
            ((float*)outp + blockIdx.z * out_zstride)[(size_t)row * N + col] = vv;
        }
      }
    }
  }
}

// ---------------- GEMM 128x128 (m97 structure): O-proj -----------------------
template <int MODE>
__global__ __launch_bounds__(256)
void gemm_bt(const unsigned short* __restrict__ A, int lda,
             const unsigned short* __restrict__ W, int ldw,
             const float* __restrict__ bias, const float* res, void* outp,
             int N, int K, size_t out_zstride) {
  __shared__ unsigned short As[128 * 32];
  __shared__ unsigned short Bs[128 * 32];
  const int t = threadIdx.x;
  const int l = t & 63;
  const int w = t >> 6;
  const int m0 = blockIdx.y << 7;
  const int n0 = blockIdx.x << 7;
  const int wr = (w >> 1) << 6;
  const int wc = (w & 1) << 6;
  const int koff = blockIdx.z * K;

  const unsigned short* Ab = A + (size_t)m0 * lda + koff;
  const unsigned short* Wb = W + (size_t)n0 * ldw + koff;

  f32x4 acc[4][4] = {};

  const int c0 = t, c1 = t + 256;
  const int ar0 = c0 >> 2, ak0 = (c0 & 3) * 8;
  const int ar1 = c1 >> 2, ak1 = (c1 & 3) * 8;
  const int lr = l & 15, lk = (l >> 4) * 8;

  for (int k0 = 0; k0 < K; k0 += 32) {
    gload_lds16(Ab + (size_t)ar0 * lda + k0 + ak0, &As[c0 * 8]);
    gload_lds16(Ab + (size_t)ar1 * lda + k0 + ak1, &As[c1 * 8]);
    gload_lds16(Wb + (size_t)ar0 * ldw + k0 + ak0, &Bs[c0 * 8]);
    gload_lds16(Wb + (size_t)ar1 * ldw + k0 + ak1, &Bs[c1 * 8]);
    __syncthreads();
    short8 a[4], b[4];
#pragma unroll
    for (int mi = 0; mi < 4; mi++)
      a[mi] = *(const short8*)&As[(wr + mi * 16 + lr) * 32 + lk];
#pragma unroll
    for (int ni = 0; ni < 4; ni++)
      b[ni] = *(const short8*)&Bs[(wc + ni * 16 + lr) * 32 + lk];
#pragma unroll
    for (int mi = 0; mi < 4; mi++)
#pragma unroll
      for (int ni = 0; ni < 4; ni++)
        acc[mi][ni] = __builtin_amdgcn_mfma_f32_16x16x32_bf16(
            a[mi], b[ni], acc[mi][ni], 0, 0, 0);
    __syncthreads();
  }

  const int lg = (l >> 4) * 4;
#pragma unroll
  for (int mi = 0; mi < 4; mi++) {
#pragma unroll
    for (int ni = 0; ni < 4; ni++) {
      int cn = n0 + wc + ni * 16 + lr;
      float bval = bias[cn];
#pragma unroll
      for (int j = 0; j < 4; j++) {
        int r = m0 + wr + mi * 16 + lg + j;
        float vv = acc[mi][ni][j] + bval;
        size_t idx = (size_t)r * N + cn;
        ((float*)outp)[idx] = vv + res[idx];
      }
    }
  }
  (void)out_zstride;
}

// ---------------- V transpose: qkv v-slice -> vt[(bh*128+d)*S + s] -----------
__global__ __launch_bounds__(256)
void vtrans_kernel(const unsigned short* __restrict__ qkv,
                   unsigned short* __restrict__ vt) {
  const int bh = blockIdx.y;
  const int b = bh >> 4, h = bh & 15;
  const int s0 = blockIdx.x * 32;
  __shared__ unsigned short tile[32][136];
  const int t = threadIdx.x;
  for (int i = 0; i < 2; i++) {
    int c = t + i * 256;
    int s = c >> 4, dc = c & 15;
    *(short8*)&tile[s][dc * 8] =
        *(const short8*)(qkv + (size_t)(b * SEQ + s0 + s) * QKV_LD + 4096 +
                         h * HEAD_DIM + dc * 8);
  }
  __syncthreads();
  const int d = t >> 1, sh = (t & 1) * 16;
  unsigned short* dst = vt + ((size_t)bh * HEAD_DIM + d) * SEQ + s0 + sh;
  short8 r0, r1;
#pragma unroll
  for (int j = 0; j < 8; j++) r0[j] = tile[sh + j][d];
#pragma unroll
  for (int j = 0; j < 8; j++) r1[j] = tile[sh + 8 + j][d];
  *(short8*)dst = r0;
  *(short8*)(dst + 8) = r1;
}

// ======== Flash attention: 8-warp 32x32 swapped-operand ======================
__global__ __launch_bounds__(512, 2)
void attn_kernel(const unsigned short* __restrict__ qkv,
                 const unsigned short* __restrict__ vt,
                 unsigned short* __restrict__ o) {
  const int bh = blockIdx.y;
  const int b = bh >> 4, h = bh & 15;
  const int q0 = blockIdx.x << 8;
  const int t = threadIdx.x, w = t >> 6, l = t & 63;
  const int ln = l & 31, hi = l >> 5;

  __shared__ unsigned short Ks[2][64 * 128];

  short8 qf[8];
  {
    const unsigned short* qb =
        qkv + (size_t)(b * SEQ + q0 + w * 32 + ln) * QKV_LD + h * HEAD_DIM +
        hi * 8;
#pragma unroll
    for (int sl = 0; sl < 8; sl++) qf[sl] = *(const short8*)(qb + sl * 16);
  }

  f32x16 oacc[4] = {};
  float mrow = -1e30f, lrow = 0.f;

  const unsigned short* kbase =
      qkv + (size_t)(b * SEQ) * QKV_LD + 2048 + h * HEAD_DIM;
  const unsigned short* vbase = vt + (size_t)bh * HEAD_DIM * SEQ;

#define STAGEK(buf, kv0_)                                                    \
  do {                                                                       \
    _Pragma("unroll") for (int i_ = 0; i_ < 2; i_++) {                       \
      int c_ = t + i_ * 512;                                                 \
      int row_ = c_ >> 4, dc_ = c_ & 15;                                     \
      int sel_ = ((dc_ * 16) ^ ((row_ & 7) << 4)) >> 1;                      \
      gload_lds16(kbase + (size_t)((kv0_) + row_) * QKV_LD + sel_,           \
                  &Ks[buf][c_ * 8]);                                         \
    }                                                                        \
  } while (0)

  STAGEK(0, 0);
  __syncthreads();

  for (int it = 0; it < SEQ / 64; ++it) {
    const int cur = it & 1;
    const int kv0 = it * 64;

    short8 vf[4][4];
#pragma unroll
    for (int db = 0; db < 4; db++)
#pragma unroll
      for (int ks = 0; ks < 4; ks++)
        vf[db][ks] = *(const short8*)(vbase + (size_t)(db * 32 + ln) * SEQ +
                                      kv0 + ks * 16 + hi * 8);

    if (it + 1 < SEQ / 64) STAGEK(cur ^ 1, kv0 + 64);

    const char* kb = (const char*)&Ks[cur][0];
    f32x16 s0 = {}, s1 = {};
#pragma unroll
    for (int sl = 0; sl < 8; sl++) {
      const int cw = (sl * 32 + hi * 16) ^ ((ln & 7) << 4);
      short8 kf0 = *(const short8*)(kb + ln * 256 + cw);
      short8 kf1 = *(const short8*)(kb + (32 + ln) * 256 + cw);
      s0 = mfma32(kf0, qf[sl], s0);
      s1 = mfma32(kf1, qf[sl], s1);
    }

    float mx = s0[0];
#pragma unroll
    for (int r = 1; r < 16; r++) mx = fmaxf(mx, s0[r]);
#pragma unroll
    for (int r = 0; r < 16; r++) mx = fmaxf(mx, s1[r]);
    {
      uint2v r2 = plswap(__float_as_uint(mx), __float_as_uint(mx));
      mx = fmaxf(__uint_as_float(r2[0]), __uint_as_float(r2[1]));
    }

    if (!__all(mx <= mrow + 8.f)) {
      float mnew = fmaxf(mrow, mx);
      float fs = exp2f(mrow - mnew);
      mrow = mnew;
      lrow *= fs;
#pragma unroll
      for (int db = 0; db < 4; db++)
#pragma unroll
        for (int r = 0; r < 16; r++) oacc[db][r] *= fs;
    }

    float p0[16], p1[16];
    float sum = 0.f;
#pragma unroll
    for (int r = 0; r < 16; r++) {
      p0[r] = exp2f(s0[r] - mrow);
      sum += p0[r];
    }
#pragma unroll
    for (int r = 0; r < 16; r++) {
      p1[r] = exp2f(s1[r] - mrow);
      sum += p1[r];
    }
    lrow += sum;

    uint4v pk[4];
#define PACKSUB(P, K0)                                                       \
  {                                                                          \
    unsigned int a_, b_;                                                     \
    uint2v r_;                                                               \
    a_ = cvtpk(P[0], P[1]); b_ = cvtpk(P[4], P[5]);                          \
    r_ = plswap(a_, b_); pk[K0][0] = r_[0]; pk[K0][2] = r_[1];               \
    a_ = cvtpk(P[2], P[3]); b_ = cvtpk(P[6], P[7]);                          \
    r_ = plswap(a_, b_); pk[K0][1] = r_[0]; pk[K0][3] = r_[1];               \
    a_ = cvtpk(P[8], P[9]); b_ = cvtpk(P[12], P[13]);                        \
    r_ = plswap(a_, b_); pk[K0 + 1][0] = r_[0]; pk[K0 + 1][2] = r_[1];       \
    a_ = cvtpk(P[10], P[11]); b_ = cvtpk(P[14], P[15]);                      \
    r_ = plswap(a_, b_); pk[K0 + 1][1] = r_[0]; pk[K0 + 1][3] = r_[1];       \
  }
    PACKSUB(p0, 0);
    PACKSUB(p1, 2);
#undef PACKSUB

#pragma unroll
    for (int db = 0; db < 4; db++)
#pragma unroll
      for (int ks = 0; ks < 4; ks++)
        oacc[db] = mfma32(vf[db][ks], __builtin_bit_cast(short8, pk[ks]),
                          oacc[db]);

    __syncthreads();
  }
#undef STAGEK

  {
    uint2v r2 = plswap(__float_as_uint(lrow), __float_as_uint(lrow));
    lrow = __uint_as_float(r2[0]) + __uint_as_float(r2[1]);
  }
  const float inv = 1.0f / lrow;
  unsigned short* ob = o + (size_t)(b * SEQ + q0 + w * 32 + ln) * D_MODEL +
                       h * HEAD_DIM + hi * 4;
#pragma unroll
  for (int db = 0; db < 4; db++)
#pragma unroll
    for (int r = 0; r < 4; r++) {
      short4v v4;
#pragma unroll
      for (int j = 0; j < 4; j++)
        v4[j] = (short)f2b(oacc[db][4 * r + j] * inv);
      *(short4v*)(ob + db * 32 + r * 8) = v4;
    }
}

// ---------------- split-K reduce: out += p0 + p1 + b2 ------------------------
__global__ __launch_bounds__(256)
void reduce2_kernel(const float* __restrict__ p0, const float* __restrict__ p1,
                    const float* __restrict__ b2, float* __restrict__ out) {
  size_t i = (size_t)blockIdx.x * 256 + threadIdx.x;
  float4 a = ((const float4*)p0)[i];
  float4 b = ((const float4*)p1)[i];
  float4 o = ((const float4*)out)[i];
  float4 bb = ((const float4*)b2)[i & 511];
  o.x += a.x + b.x + bb.x;
  o.y += a.y + b.y + bb.y;
  o.z += a.z + b.z + bb.z;
  o.w += a.w + b.w + bb.w;
  ((float4*)out)[i] = o;
}

// ---------------- host: launch sequence --------------------------------------
extern "C" void kernel_launch(void* const* d_in, const int* in_sizes, int n_in,
                              void* d_out, int out_size, void* d_ws,
                              size_t ws_size, hipStream_t stream) {
  (void)in_sizes; (void)n_in; (void)out_size; (void)ws_size;
  const float* x   = (const float*)d_in[0];
  const float* Wq  = (const float*)d_in[1];
  const float* bq  = (const float*)d_in[2];
  const float* Wk  = (const float*)d_in[3];
  const float* bk  = (const float*)d_in[4];
  const float* Wv  = (const float*)d_in[5];
  const float* bv  = (const float*)d_in[6];
  const float* Wo  = (const float*)d_in[7];
  const float* bo  = (const float*)d_in[8];
  const float* rot = (const float*)d_in[9];
  const float* n1w = (const float*)d_in[10];
  const float* n2w = (const float*)d_in[11];
  const float* W1  = (const float*)d_in[12];
  const float* b1  = (const float*)d_in[13];
  const float* W2  = (const float*)d_in[14];
  const float* b2  = (const float*)d_in[15];
  float* out = (float*)d_out;
  char* ws = (char*)d_ws;

  const size_t SZ_D2  = (size_t)D_MODEL * D_MODEL * 2;   // 8 MiB
  const size_t SZ_ACT = (size_t)M_TOK * D_MODEL * 2;     // 16 MiB
  const size_t SZ_W1  = (size_t)2 * D_FF * D_MODEL * 2;  // 64 MiB
  const size_t SZ_W2  = (size_t)D_MODEL * D_FF * 2;      // 32 MiB
  const size_t SZ_G   = (size_t)M_TOK * 2 * D_FF * 2;    // 128 MiB

  size_t off = 0;
  auto alloc = [&](size_t sz) { size_t o = off; off += (sz + 255) & ~(size_t)255; return o; };
  unsigned short* wqkv_b = (unsigned short*)(ws + alloc(3 * SZ_D2));  // at ws+0
  unsigned short* wo_b   = (unsigned short*)(ws + alloc(SZ_D2));
  unsigned short* w1_b   = (unsigned short*)(ws + alloc(SZ_W1));     // permuted W1'
  unsigned short* w2_b   = (unsigned short*)(ws + alloc(SZ_W2));
  float*          biasq  = (float*)(ws + alloc(QKV_LD * 4));
  float*          b1p    = (float*)(ws + alloc(2 * D_FF * 4));
  unsigned short* h2_b   = (unsigned short*)(ws + alloc(SZ_ACT));
  char* pool = ws + alloc(SZ_G);
  // phase 1 overlay in pool: h | qkv | vt | o   (16+48+16+16 = 96 MiB)
  unsigned short* h_b   = (unsigned short*)(pool);
  unsigned short* qkv_b = (unsigned short*)(pool + SZ_ACT);
  unsigned short* vt_b  = (unsigned short*)(pool + 4 * SZ_ACT);
  unsigned short* o_b   = (unsigned short*)(pool + 5 * SZ_ACT);
  // phase 2 overlay: ff (4096 x 8192 bf16 = 64 MiB) occupies pool start
  unsigned short* ff_b  = (unsigned short*)(pool);
  // split-K partials overlay the (then-dead) wqkv/wo/w1 region
  float* p0 = (float*)ws;
  float* p1 = p0 + (size_t)M_TOK * D_MODEL;

  // weights -> bf16 (Q,K,V concatenated row-wise; Wq pre-scaled by QSCALE)
  cvt_kernel<<<1024, 256, 0, stream>>>(Wq, wqkv_b, D_MODEL * D_MODEL / 8, QSCALE);
  cvt_kernel<<<1024, 256, 0, stream>>>(Wk, wqkv_b + (size_t)D_MODEL * D_MODEL, D_MODEL * D_MODEL / 8, 1.0f);
  cvt_kernel<<<1024, 256, 0, stream>>>(Wv, wqkv_b + (size_t)2 * D_MODEL * D_MODEL, D_MODEL * D_MODEL / 8, 1.0f);
  cvt_kernel<<<1024, 256, 0, stream>>>(Wo, wo_b, D_MODEL * D_MODEL / 8, 1.0f);
  cvt_w1p_kernel<<<2048, 256, 0, stream>>>(W1, w1_b);
  cvt_kernel<<<2048, 256, 0, stream>>>(W2, w2_b, D_MODEL * D_FF / 8, 1.0f);
  biasqkv_kernel<<<QKV_LD / 256, 256, 0, stream>>>(bq, bk, bv, rot, biasq);
  permb1_kernel<<<2 * D_FF / 256, 256, 0, stream>>>(b1, b1p);

  // norm1 -> h
  rmsnorm_kernel<<<M_TOK, 256, 0, stream>>>(x, n1w, h_b);

  // fused QKV projection (2-phase 256^2, 32x32 MFMA); grid = (M-tiles, N-tiles)
  gemm_p8<0><<<dim3(M_TOK / 256, QKV_LD / 256), 512, 0, stream>>>(
      h_b, D_MODEL, wqkv_b, D_MODEL, biasq, qkv_b, QKV_LD, D_MODEL, 0);

  // V transpose + attention
  vtrans_kernel<<<dim3(SEQ / 32, BATCH * N_HEADS), 256, 0, stream>>>(qkv_b, vt_b);
  attn_kernel<<<dim3(SEQ / 256, BATCH * N_HEADS), 512, 0, stream>>>(qkv_b, vt_b, o_b);

  // O projection + residual -> d_out (f32), 128^2 structure
  gemm_bt<1><<<dim3(D_MODEL / 128, M_TOK / 128), 256, 0, stream>>>(
      o_b, D_MODEL, wo_b, D_MODEL, bo, x, out, D_MODEL, D_MODEL, 0);

  // norm2 -> h2
  rmsnorm_kernel<<<M_TOK, 256, 0, stream>>>(out, n2w, h2_b);

  // W1 + fused SwiGLU -> ff (2-phase 256^2, MODE 3)
  gemm_p8<3><<<dim3(M_TOK / 256, 2 * D_FF / 256), 512, 0, stream>>>(
      h2_b, D_MODEL, w1_b, D_MODEL, b1p, ff_b, 2 * D_FF, D_MODEL, 0);

  // W2 split-K on gemm_p8 (z=2): A = ff [4096][8192]
  gemm_p8<2><<<dim3(M_TOK / 256, D_MODEL / 256, 2), 512, 0, stream>>>(
      ff_b, D_FF, w2_b, D_FF, nullptr, p0, D_MODEL, D_FF / 2,
      (size_t)M_TOK * D_MODEL);

  // out += p0 + p1 + b2
  reduce2_kernel<<<(M_TOK * D_MODEL / 4) / 256, 256, 0, stream>>>(p0, p1, b2, out);
}

// Round 12
// 915.417 us; speedup vs baseline: 1.0157x; 1.0157x over previous
//
#include <hip/hip_runtime.h>
#include <hip/hip_bf16.h>

#define D_MODEL 2048
#define N_HEADS 16
#define HEAD_DIM 128
#define D_FF 8192
#define BATCH 2
#define SEQ 2048
#define M_TOK (BATCH * SEQ)
#define QKV_LD 6144
// 1/sqrt(128) * log2(e): folded into Wq/bq so scores are in exp2 domain
#define QSCALE 0.12751744f

typedef __attribute__((ext_vector_type(8))) short short8;
typedef __attribute__((ext_vector_type(4))) short short4v;
typedef __attribute__((ext_vector_type(4))) float f32x4;
typedef __attribute__((ext_vector_type(16))) float f32x16;
typedef __attribute__((ext_vector_type(2))) unsigned int uint2v;
typedef __attribute__((ext_vector_type(4))) unsigned int uint4v;

__device__ __forceinline__ unsigned short f2b(float f) {
  __hip_bfloat16 h = __float2bfloat16(f);
  return *reinterpret_cast<unsigned short*>(&h);
}
__device__ __forceinline__ float b2f(unsigned short u) {
  unsigned int x = ((unsigned int)u) << 16;
  return __uint_as_float(x);
}

__device__ __forceinline__ void gload_lds16(const void* gsrc, void* ldst) {
  __builtin_amdgcn_global_load_lds(
      (const __attribute__((address_space(1))) void*)gsrc,
      (__attribute__((address_space(3))) void*)ldst, 16, 0, 0);
}

__device__ __forceinline__ f32x16 mfma32(short8 a, short8 b, f32x16 c) {
  return __builtin_amdgcn_mfma_f32_32x32x16_bf16(a, b, c, 0, 0, 0);
}
__device__ __forceinline__ unsigned int cvtpk(float lo, float hi) {
  unsigned int r;
  asm("v_cvt_pk_bf16_f32 %0, %1, %2" : "=v"(r) : "v"(lo), "v"(hi));
  return r;
}
__device__ __forceinline__ uint2v plswap(unsigned int a, unsigned int b) {
  return __builtin_amdgcn_permlane32_swap(a, b, false, false);
}

// ---------------- f32 -> bf16 convert (optional scale) -----------------------
__global__ __launch_bounds__(256)
void cvt_kernel(const float* __restrict__ src, unsigned short* __restrict__ dst,
                int nchunks, float scale) {
  int i = blockIdx.x * blockDim.x + threadIdx.x;
  int stride = gridDim.x * blockDim.x;
  for (int c = i; c < nchunks; c += stride) {
    const float4 a = *(const float4*)(src + (size_t)c * 8);
    const float4 b = *(const float4*)(src + (size_t)c * 8 + 4);
    short8 r;
    r[0] = f2b(a.x * scale); r[1] = f2b(a.y * scale);
    r[2] = f2b(a.z * scale); r[3] = f2b(a.w * scale);
    r[4] = f2b(b.x * scale); r[5] = f2b(b.y * scale);
    r[6] = f2b(b.z * scale); r[7] = f2b(b.w * scale);
    *(short8*)(dst + (size_t)c * 8) = r;
  }
}

// ---------------- W1 -> bf16 with row interleave -----------------------------
// dst row r' = [b = r'>>6][half = (r'>>5)&1][r'&31] <- src row half*8192+b*32+(r'&31)
__global__ __launch_bounds__(256)
void cvt_w1p_kernel(const float* __restrict__ src,
                    unsigned short* __restrict__ dst) {
  int i = blockIdx.x * blockDim.x + threadIdx.x;
  int stride = gridDim.x * blockDim.x;
  const int total = 2 * D_FF * (D_MODEL / 8);
  for (int c = i; c < total; c += stride) {
    int rp = c >> 8, col8 = c & 255;
    int b = rp >> 6, half = (rp >> 5) & 1;
    int rs = half * D_FF + b * 32 + (rp & 31);
    const float* s = src + (size_t)rs * D_MODEL + col8 * 8;
    const float4 a = *(const float4*)s;
    const float4 bb = *(const float4*)(s + 4);
    short8 r;
    r[0] = f2b(a.x); r[1] = f2b(a.y); r[2] = f2b(a.z); r[3] = f2b(a.w);
    r[4] = f2b(bb.x); r[5] = f2b(bb.y); r[6] = f2b(bb.z); r[7] = f2b(bb.w);
    *(short8*)(dst + (size_t)c * 8) = r;
  }
}

// ---------------- b1 permuted to match W1' row order -------------------------
__global__ void permb1_kernel(const float* __restrict__ b1,
                              float* __restrict__ b1p) {
  int i = blockIdx.x * 256 + threadIdx.x;
  int b = i >> 6, half = (i >> 5) & 1;
  b1p[i] = b1[half * D_FF + b * 32 + (i & 31)];
}

// ---------------- concat bias: [(bq+rot)*QSCALE | bk | bv] -------------------
__global__ void biasqkv_kernel(const float* __restrict__ bq,
                               const float* __restrict__ bk,
                               const float* __restrict__ bv,
                               const float* __restrict__ rot,
                               float* __restrict__ outp) {
  int i = blockIdx.x * 256 + threadIdx.x;
  float v;
  if (i < 2048) v = (bq[i] + rot[i & (HEAD_DIM - 1)]) * QSCALE;
  else if (i < 4096) v = bk[i - 2048];
  else v = bv[i - 4096];
  outp[i] = v;
}

// ---------------- RMSNorm: f32 in -> bf16 out --------------------------------
__global__ __launch_bounds__(256)
void rmsnorm_kernel(const float* __restrict__ x, const float* __restrict__ wv,
                    unsigned short* __restrict__ outp) {
  const int row = blockIdx.x;
  const float* xr = x + (size_t)row * D_MODEL;
  const int base = threadIdx.x * 8;
  float4 a = *(const float4*)(xr + base);
  float4 c = *(const float4*)(xr + base + 4);
  float ss = a.x * a.x + a.y * a.y + a.z * a.z + a.w * a.w +
             c.x * c.x + c.y * c.y + c.z * c.z + c.w * c.w;
#pragma unroll
  for (int m = 1; m < 64; m <<= 1) ss += __shfl_xor(ss, m);
  __shared__ float red[4];
  if ((threadIdx.x & 63) == 0) red[threadIdx.x >> 6] = ss;
  __syncthreads();
  float tot = red[0] + red[1] + red[2] + red[3];
  float sc = rsqrtf(tot * (1.0f / D_MODEL) + 1e-8f);
  float4 w0 = *(const float4*)(wv + base);
  float4 w1 = *(const float4*)(wv + base + 4);
  short8 r;
  r[0] = f2b(a.x * sc * w0.x); r[1] = f2b(a.y * sc * w0.y);
  r[2] = f2b(a.z * sc * w0.z); r[3] = f2b(a.w * sc * w0.w);
  r[4] = f2b(c.x * sc * w1.x); r[5] = f2b(c.y * sc * w1.y);
  r[6] = f2b(c.z * sc * w1.z); r[7] = f2b(c.w * sc * w1.w);
  *(short8*)(outp + (size_t)row * D_MODEL + base) = r;
}

// ===== GEMM 256x256, BK=64, 2-phase/K-tile pipelined, 32x32x16 MFMA ==========
// Grid: (x = N-tiles, y = M-tiles) — r10-proven orientation (r11's swap cost
// +100 MB FETCH; reverted). Swizzle: r8-proven (row&7)<<4 via pre-swizzled
// global source at staging + same XOR on reads (rule 21 both-sides).
// Phase p of a K-tile reads A-half p (sub-blocks 2p, 2p+1); B cached in regs
// from phase 0; 16 MFMA_32x32x16 per barrier window; vmcnt(4) once per K-tile.
// MODE 0: bf16 out + bias.  MODE 2: f32 partial out.  MODE 3: swiglu-fused
// bf16 out (W1': rows interleaved so cb0 = x1, cb1 = x2; out LD = N/2).
template <int MODE>
__global__ __launch_bounds__(512, 2)
void gemm_p8(const unsigned short* __restrict__ A, int lda,
             const unsigned short* __restrict__ W, int ldw,
             const float* __restrict__ bias, void* __restrict__ outp,
             int N, int K, size_t out_zstride) {
  __shared__ unsigned short AL[2][2][128 * 64];
  __shared__ unsigned short BL[2][2][128 * 64];
  const int t = threadIdx.x;
  const int l = t & 63, w = t >> 6;
  const int wm = w >> 2, wn = w & 3;
  const int ln = l & 31, hi = l >> 5;
  const int m0 = blockIdx.y << 8, n0 = blockIdx.x << 8;  // r10 orientation
  const int koff = blockIdx.z * K;

  // staging: half-tile = 128 rows x 64 k; thread t stages chunks t, t+512
  const int r0 = t >> 3;
  const int cb16 = (t & 7) * 16;
  const int sel = ((cb16 ^ ((r0 & 7) << 4)) >> 1);  // r8 swizzle
  const unsigned short* Abase = A + (size_t)m0 * lda + koff;
  const unsigned short* Wbase = W + (size_t)n0 * ldw + koff;
  const int d0e = t * 8, d1e = (t + 512) * 8;

#define STAGE(XL, Xb, ld, dd, h, ktd)                                        \
  do {                                                                       \
    const unsigned short* s_ =                                               \
        (Xb) + (size_t)((h) * 128 + r0) * (ld) + (ktd) * 64 + sel;           \
    gload_lds16(s_, &XL[dd][h][d0e]);                                        \
    gload_lds16(s_ + (size_t)64 * (ld), &XL[dd][h][d1e]);                    \
  } while (0)

  const int swz = (ln & 7) << 4;                // r8 swizzle for all reads
  const int hb = wn >> 1;                       // B half for this wave
  const int browb = ((wn & 1) * 64 + ln) * 128; // B row base byte

  f32x16 acc[4][2] = {};
  short8 bf[2][4];  // B-frags held across both phases of a K-tile

#define READB(dd)                                                            \
  do {                                                                       \
    const char* Bb_ = (const char*)&BL[dd][hb][0];                           \
    _Pragma("unroll") for (int cb_ = 0; cb_ < 2; cb_++)                      \
      _Pragma("unroll") for (int ks_ = 0; ks_ < 4; ks_++)                    \
        bf[cb_][ks_] = *(const short8*)(Bb_ + browb + cb_ * 4096 +           \
                                        ((ks_ * 32 + hi * 16) ^ swz));       \
  } while (0)

// PHASE2(dd, p): reads A-half p (sub-blocks 2p, 2p+1), 16 MFMA.
#define PHASE2(dd, p, STAGE_STMT, VM_STMT)                                   \
  do {                                                                       \
    const char* Ab_ = (const char*)&AL[dd][p][0];                            \
    short8 af_[2][4];                                                        \
    if ((p) == 0) READB(dd);                                                 \
    _Pragma("unroll") for (int sb_ = 0; sb_ < 2; sb_++) {                    \
      _Pragma("unroll") for (int ks_ = 0; ks_ < 4; ks_++)                    \
        af_[sb_][ks_] = *(const short8*)(Ab_ +                               \
                                         (wm * 64 + sb_ * 32 + ln) * 128 +   \
                                         ((ks_ * 32 + hi * 16) ^ swz));      \
    }                                                                        \
    STAGE_STMT;                                                              \
    __builtin_amdgcn_sched_barrier(0);                                       \
    VM_STMT;                                                                 \
    __builtin_amdgcn_sched_barrier(0);                                       \
    __builtin_amdgcn_s_barrier();                                            \
    __builtin_amdgcn_sched_barrier(0);                                       \
    __builtin_amdgcn_s_setprio(1);                                           \
    _Pragma("unroll") for (int sb_ = 0; sb_ < 2; sb_++)                      \
      _Pragma("unroll") for (int cb_ = 0; cb_ < 2; cb_++)                    \
        _Pragma("unroll") for (int ks_ = 0; ks_ < 4; ks_++)                  \
          acc[2 * (p) + sb_][cb_] =                                          \
              mfma32(af_[sb_][ks_], bf[cb_][ks_], acc[2 * (p) + sb_][cb_]);  \
    __builtin_amdgcn_s_setprio(0);                                           \
    __builtin_amdgcn_sched_barrier(0);                                       \
    __builtin_amdgcn_s_barrier();                                            \
    __builtin_amdgcn_sched_barrier(0);                                       \
  } while (0)

  const int NT = K >> 6;

  // prologue: kt0 fully, kt1's A-half0 + B-half0 (proven r5-r10 chain)
  STAGE(AL, Abase, lda, 0, 0, 0);
  STAGE(AL, Abase, lda, 0, 1, 0);
  STAGE(BL, Wbase, ldw, 0, 0, 0);
  STAGE(BL, Wbase, ldw, 0, 1, 0);
  STAGE(AL, Abase, lda, 1, 0, 1);
  STAGE(BL, Wbase, ldw, 1, 0, 1);
  asm volatile("s_waitcnt vmcnt(4)" ::: "memory");
  __builtin_amdgcn_sched_barrier(0);
  __builtin_amdgcn_s_barrier();
  __builtin_amdgcn_sched_barrier(0);

  for (int kt = 0; kt < NT; kt += 2) {
    // ---- K-tile kt (dbuf 0) ----
    PHASE2(0, 0,
           {
             if (kt + 1 < NT) {
               STAGE(BL, Wbase, ldw, 1, 1, kt + 1);
               STAGE(AL, Abase, lda, 1, 1, kt + 1);
             }
           },
           {});
    PHASE2(0, 1,
           {
             if (kt + 2 < NT) {
               STAGE(AL, Abase, lda, 0, 0, kt + 2);
               STAGE(BL, Wbase, ldw, 0, 0, kt + 2);
             }
           },
           {
             if (kt + 2 < NT)
               asm volatile("s_waitcnt vmcnt(4)" ::: "memory");
             else
               asm volatile("s_waitcnt vmcnt(0)" ::: "memory");
           });
    // ---- K-tile kt+1 (dbuf 1) ----
    PHASE2(1, 0,
           {
             if (kt + 2 < NT) {
               STAGE(BL, Wbase, ldw, 0, 1, kt + 2);
               STAGE(AL, Abase, lda, 0, 1, kt + 2);
             }
           },
           {});
    PHASE2(1, 1,
           {
             if (kt + 3 < NT) {
               STAGE(AL, Abase, lda, 1, 0, kt + 3);
               STAGE(BL, Wbase, ldw, 1, 0, kt + 3);
             }
           },
           {
             if (kt + 3 < NT)
               asm volatile("s_waitcnt vmcnt(4)" ::: "memory");
             else
               asm volatile("s_waitcnt vmcnt(0)" ::: "memory");
           });
  }
#undef PHASE2
#undef READB
#undef STAGE

  // epilogue: row = m0+(rb>>1)*128+wm*64+(rb&1)*32+(r&3)+8*(r>>2)+4*hi
#pragma unroll
  for (int rb = 0; rb < 4; rb++) {
    const int rowb = m0 + (rb >> 1) * 128 + wm * 64 + (rb & 1) * 32 + 4 * hi;
    if (MODE == 3) {
      const int col0 = n0 + wn * 64 + ln;
      const float b1v = bias[col0];
      const float b2v = bias[col0 + 32];
      const int jout = (n0 >> 1) + wn * 32 + ln;
#pragma unroll
      for (int r = 0; r < 16; r++) {
        const int row = rowb + (r & 3) + 8 * (r >> 2);
        float x1 = acc[rb][0][r] + b1v;
        float x2 = acc[rb][1][r] + b2v;
        float sg = x2 / (1.0f + __expf(-x2));
        ((unsigned short*)outp)[(size_t)row * (N >> 1) + jout] = f2b(x1 * sg);
      }
    } else {
#pragma unroll
      for (int cb = 0; cb < 2; cb++) {
        const int col = n0 + wn * 64 + cb * 32 + ln;
        const float bv = (MODE == 0) ? bias[col] : 0.0f;
#pragma unroll
        for (int r = 0; r < 16; r++) {
          const int row = rowb + (r & 3) + 8 * (r >> 2);
          const float vv = acc[rb][cb][r] + bv;
          if (MODE == 0)
            ((unsigned short*)outp)[(size_t)row * N + col] = f2b(vv);
          else
            ((float*)outp + blockIdx.z * out_zstride)[(size_t)row * N + col] = vv;
        }
      }
    }
  }
}

// ---------------- GEMM 128x128 (m97 structure): O-proj -----------------------
template <int MODE>
__global__ __launch_bounds__(256)
void gemm_bt(const unsigned short* __restrict__ A, int lda,
             const unsigned short* __restrict__ W, int ldw,
             const float* __restrict__ bias, const float* res, void* outp,
             int N, int K, size_t out_zstride) {
  __shared__ unsigned short As[128 * 32];
  __shared__ unsigned short Bs[128 * 32];
  const int t = threadIdx.x;
  const int l = t & 63;
  const int w = t >> 6;
  const int m0 = blockIdx.y << 7;
  const int n0 = blockIdx.x << 7;
  const int wr = (w >> 1) << 6;
  const int wc = (w & 1) << 6;
  const int koff = blockIdx.z * K;

  const unsigned short* Ab = A + (size_t)m0 * lda + koff;
  const unsigned short* Wb = W + (size_t)n0 * ldw + koff;

  f32x4 acc[4][4] = {};

  const int c0 = t, c1 = t + 256;
  const int ar0 = c0 >> 2, ak0 = (c0 & 3) * 8;
  const int ar1 = c1 >> 2, ak1 = (c1 & 3) * 8;
  const int lr = l & 15, lk = (l >> 4) * 8;

  for (int k0 = 0; k0 < K; k0 += 32) {
    gload_lds16(Ab + (size_t)ar0 * lda + k0 + ak0, &As[c0 * 8]);
    gload_lds16(Ab + (size_t)ar1 * lda + k0 + ak1, &As[c1 * 8]);
    gload_lds16(Wb + (size_t)ar0 * ldw + k0 + ak0, &Bs[c0 * 8]);
    gload_lds16(Wb + (size_t)ar1 * ldw + k0 + ak1, &Bs[c1 * 8]);
    __syncthreads();
    short8 a[4], b[4];
#pragma unroll
    for (int mi = 0; mi < 4; mi++)
      a[mi] = *(const short8*)&As[(wr + mi * 16 + lr) * 32 + lk];
#pragma unroll
    for (int ni = 0; ni < 4; ni++)
      b[ni] = *(const short8*)&Bs[(wc + ni * 16 + lr) * 32 + lk];
#pragma unroll
    for (int mi = 0; mi < 4; mi++)
#pragma unroll
      for (int ni = 0; ni < 4; ni++)
        acc[mi][ni] = __builtin_amdgcn_mfma_f32_16x16x32_bf16(
            a[mi], b[ni], acc[mi][ni], 0, 0, 0);
    __syncthreads();
  }

  const int lg = (l >> 4) * 4;
#pragma unroll
  for (int mi = 0; mi < 4; mi++) {
#pragma unroll
    for (int ni = 0; ni < 4; ni++) {
      int cn = n0 + wc + ni * 16 + lr;
      float bval = bias[cn];
#pragma unroll
      for (int j = 0; j < 4; j++) {
        int r = m0 + wr + mi * 16 + lg + j;
        float vv = acc[mi][ni][j] + bval;
        size_t idx = (size_t)r * N + cn;
        ((float*)outp)[idx] = vv + res[idx];
      }
    }
  }
  (void)out_zstride;
}

// ---------------- V transpose: qkv v-slice -> vt[(bh*128+d)*S + s] -----------
__global__ __launch_bounds__(256)
void vtrans_kernel(const unsigned short* __restrict__ qkv,
                   unsigned short* __restrict__ vt) {
  const int bh = blockIdx.y;
  const int b = bh >> 4, h = bh & 15;
  const int s0 = blockIdx.x * 32;
  __shared__ unsigned short tile[32][136];
  const int t = threadIdx.x;
  for (int i = 0; i < 2; i++) {
    int c = t + i * 256;
    int s = c >> 4, dc = c & 15;
    *(short8*)&tile[s][dc * 8] =
        *(const short8*)(qkv + (size_t)(b * SEQ + s0 + s) * QKV_LD + 4096 +
                         h * HEAD_DIM + dc * 8);
  }
  __syncthreads();
  const int d = t >> 1, sh = (t & 1) * 16;
  unsigned short* dst = vt + ((size_t)bh * HEAD_DIM + d) * SEQ + s0 + sh;
  short8 r0, r1;
#pragma unroll
  for (int j = 0; j < 8; j++) r0[j] = tile[sh + j][d];
#pragma unroll
  for (int j = 0; j < 8; j++) r1[j] = tile[sh + 8 + j][d];
  *(short8*)dst = r0;
  *(short8*)(dst + 8) = r1;
}

// ======== Flash attention: 8-warp 32x32 swapped-operand ======================
__global__ __launch_bounds__(512, 2)
void attn_kernel(const unsigned short* __restrict__ qkv,
                 const unsigned short* __restrict__ vt,
                 unsigned short* __restrict__ o) {
  const int bh = blockIdx.y;
  const int b = bh >> 4, h = bh & 15;
  const int q0 = blockIdx.x << 8;
  const int t = threadIdx.x, w = t >> 6, l = t & 63;
  const int ln = l & 31, hi = l >> 5;

  __shared__ unsigned short Ks[2][64 * 128];

  short8 qf[8];
  {
    const unsigned short* qb =
        qkv + (size_t)(b * SEQ + q0 + w * 32 + ln) * QKV_LD + h * HEAD_DIM +
        hi * 8;
#pragma unroll
    for (int sl = 0; sl < 8; sl++) qf[sl] = *(const short8*)(qb + sl * 16);
  }

  f32x16 oacc[4] = {};
  float mrow = -1e30f, lrow = 0.f;

  const unsigned short* kbase =
      qkv + (size_t)(b * SEQ) * QKV_LD + 2048 + h * HEAD_DIM;
  const unsigned short* vbase = vt + (size_t)bh * HEAD_DIM * SEQ;

#define STAGEK(buf, kv0_)                                                    \
  do {                                                                       \
    _Pragma("unroll") for (int i_ = 0; i_ < 2; i_++) {                       \
      int c_ = t + i_ * 512;                                                 \
      int row_ = c_ >> 4, dc_ = c_ & 15;                                     \
      int sel_ = ((dc_ * 16) ^ ((row_ & 7) << 4)) >> 1;                      \
      gload_lds16(kbase + (size_t)((kv0_) + row_) * QKV_LD + sel_,           \
                  &Ks[buf][c_ * 8]);                                         \
    }                                                                        \
  } while (0)

  STAGEK(0, 0);
  __syncthreads();

  for (int it = 0; it < SEQ / 64; ++it) {
    const int cur = it & 1;
    const int kv0 = it * 64;

    short8 vf[4][4];
#pragma unroll
    for (int db = 0; db < 4; db++)
#pragma unroll
      for (int ks = 0; ks < 4; ks++)
        vf[db][ks] = *(const short8*)(vbase + (size_t)(db * 32 + ln) * SEQ +
                                      kv0 + ks * 16 + hi * 8);

    if (it + 1 < SEQ / 64) STAGEK(cur ^ 1, kv0 + 64);

    const char* kb = (const char*)&Ks[cur][0];
    f32x16 s0 = {}, s1 = {};
#pragma unroll
    for (int sl = 0; sl < 8; sl++) {
      const int cw = (sl * 32 + hi * 16) ^ ((ln & 7) << 4);
      short8 kf0 = *(const short8*)(kb + ln * 256 + cw);
      short8 kf1 = *(const short8*)(kb + (32 + ln) * 256 + cw);
      s0 = mfma32(kf0, qf[sl], s0);
      s1 = mfma32(kf1, qf[sl], s1);
    }

    float mx = s0[0];
#pragma unroll
    for (int r = 1; r < 16; r++) mx = fmaxf(mx, s0[r]);
#pragma unroll
    for (int r = 0; r < 16; r++) mx = fmaxf(mx, s1[r]);
    {
      uint2v r2 = plswap(__float_as_uint(mx), __float_as_uint(mx));
      mx = fmaxf(__uint_as_float(r2[0]), __uint_as_float(r2[1]));
    }

    if (!__all(mx <= mrow + 8.f)) {
      float mnew = fmaxf(mrow, mx);
      float fs = exp2f(mrow - mnew);
      mrow = mnew;
      lrow *= fs;
#pragma unroll
      for (int db = 0; db < 4; db++)
#pragma unroll
        for (int r = 0; r < 16; r++) oacc[db][r] *= fs;
    }

    float p0[16], p1[16];
    float sum = 0.f;
#pragma unroll
    for (int r = 0; r < 16; r++) {
      p0[r] = exp2f(s0[r] - mrow);
      sum += p0[r];
    }
#pragma unroll
    for (int r = 0; r < 16; r++) {
      p1[r] = exp2f(s1[r] - mrow);
      sum += p1[r];
    }
    lrow += sum;

    uint4v pk[4];
#define PACKSUB(P, K0)                                                       \
  {                                                                          \
    unsigned int a_, b_;                                                     \
    uint2v r_;                                                               \
    a_ = cvtpk(P[0], P[1]); b_ = cvtpk(P[4], P[5]);                          \
    r_ = plswap(a_, b_); pk[K0][0] = r_[0]; pk[K0][2] = r_[1];               \
    a_ = cvtpk(P[2], P[3]); b_ = cvtpk(P[6], P[7]);                          \
    r_ = plswap(a_, b_); pk[K0][1] = r_[0]; pk[K0][3] = r_[1];               \
    a_ = cvtpk(P[8], P[9]); b_ = cvtpk(P[12], P[13]);                        \
    r_ = plswap(a_, b_); pk[K0 + 1][0] = r_[0]; pk[K0 + 1][2] = r_[1];       \
    a_ = cvtpk(P[10], P[11]); b_ = cvtpk(P[14], P[15]);                      \
    r_ = plswap(a_, b_); pk[K0 + 1][1] = r_[0]; pk[K0 + 1][3] = r_[1];       \
  }
    PACKSUB(p0, 0);
    PACKSUB(p1, 2);
#undef PACKSUB

#pragma unroll
    for (int db = 0; db < 4; db++)
#pragma unroll
      for (int ks = 0; ks < 4; ks++)
        oacc[db] = mfma32(vf[db][ks], __builtin_bit_cast(short8, pk[ks]),
                          oacc[db]);

    __syncthreads();
  }
#undef STAGEK

  {
    uint2v r2 = plswap(__float_as_uint(lrow), __float_as_uint(lrow));
    lrow = __uint_as_float(r2[0]) + __uint_as_float(r2[1]);
  }
  const float inv = 1.0f / lrow;
  unsigned short* ob = o + (size_t)(b * SEQ + q0 + w * 32 + ln) * D_MODEL +
                       h * HEAD_DIM + hi * 4;
#pragma unroll
  for (int db = 0; db < 4; db++)
#pragma unroll
    for (int r = 0; r < 4; r++) {
      short4v v4;
#pragma unroll
      for (int j = 0; j < 4; j++)
        v4[j] = (short)f2b(oacc[db][4 * r + j] * inv);
      *(short4v*)(ob + db * 32 + r * 8) = v4;
    }
}

// ---------------- split-K reduce: out += p0 + p1 + b2 ------------------------
__global__ __launch_bounds__(256)
void reduce2_kernel(const float* __restrict__ p0, const float* __restrict__ p1,
                    const float* __restrict__ b2, float* __restrict__ out) {
  size_t i = (size_t)blockIdx.x * 256 + threadIdx.x;
  float4 a = ((const float4*)p0)[i];
  float4 b = ((const float4*)p1)[i];
  float4 o = ((const float4*)out)[i];
  float4 bb = ((const float4*)b2)[i & 511];
  o.x += a.x + b.x + bb.x;
  o.y += a.y + b.y + bb.y;
  o.z += a.z + b.z + bb.z;
  o.w += a.w + b.w + bb.w;
  ((float4*)out)[i] = o;
}

// ---------------- host: launch sequence --------------------------------------
extern "C" void kernel_launch(void* const* d_in, const int* in_sizes, int n_in,
                              void* d_out, int out_size, void* d_ws,
                              size_t ws_size, hipStream_t stream) {
  (void)in_sizes; (void)n_in; (void)out_size; (void)ws_size;
  const float* x   = (const float*)d_in[0];
  const float* Wq  = (const float*)d_in[1];
  const float* bq  = (const float*)d_in[2];
  const float* Wk  = (const float*)d_in[3];
  const float* bk  = (const float*)d_in[4];
  const float* Wv  = (const float*)d_in[5];
  const float* bv  = (const float*)d_in[6];
  const float* Wo  = (const float*)d_in[7];
  const float* bo  = (const float*)d_in[8];
  const float* rot = (const float*)d_in[9];
  const float* n1w = (const float*)d_in[10];
  const float* n2w = (const float*)d_in[11];
  const float* W1  = (const float*)d_in[12];
  const float* b1  = (const float*)d_in[13];
  const float* W2  = (const float*)d_in[14];
  const float* b2  = (const float*)d_in[15];
  float* out = (float*)d_out;
  char* ws = (char*)d_ws;

  const size_t SZ_D2  = (size_t)D_MODEL * D_MODEL * 2;   // 8 MiB
  const size_t SZ_ACT = (size_t)M_TOK * D_MODEL * 2;     // 16 MiB
  const size_t SZ_W1  = (size_t)2 * D_FF * D_MODEL * 2;  // 64 MiB
  const size_t SZ_W2  = (size_t)D_MODEL * D_FF * 2;      // 32 MiB
  const size_t SZ_G   = (size_t)M_TOK * 2 * D_FF * 2;    // 128 MiB

  size_t off = 0;
  auto alloc = [&](size_t sz) { size_t o = off; off += (sz + 255) & ~(size_t)255; return o; };
  unsigned short* wqkv_b = (unsigned short*)(ws + alloc(3 * SZ_D2));  // at ws+0
  unsigned short* wo_b   = (unsigned short*)(ws + alloc(SZ_D2));
  unsigned short* w1_b   = (unsigned short*)(ws + alloc(SZ_W1));     // permuted W1'
  unsigned short* w2_b   = (unsigned short*)(ws + alloc(SZ_W2));
  float*          biasq  = (float*)(ws + alloc(QKV_LD * 4));
  float*          b1p    = (float*)(ws + alloc(2 * D_FF * 4));
  unsigned short* h2_b   = (unsigned short*)(ws + alloc(SZ_ACT));
  char* pool = ws + alloc(SZ_G);
  // phase 1 overlay in pool: h | qkv | vt | o   (16+48+16+16 = 96 MiB)
  unsigned short* h_b   = (unsigned short*)(pool);
  unsigned short* qkv_b = (unsigned short*)(pool + SZ_ACT);
  unsigned short* vt_b  = (unsigned short*)(pool + 4 * SZ_ACT);
  unsigned short* o_b   = (unsigned short*)(pool + 5 * SZ_ACT);
  // phase 2 overlay: ff (4096 x 8192 bf16 = 64 MiB) occupies pool start
  unsigned short* ff_b  = (unsigned short*)(pool);
  // split-K partials overlay the (then-dead) wqkv/wo/w1 region
  float* p0 = (float*)ws;
  float* p1 = p0 + (size_t)M_TOK * D_MODEL;

  // weights -> bf16 (Q,K,V concatenated row-wise; Wq pre-scaled by QSCALE)
  cvt_kernel<<<1024, 256, 0, stream>>>(Wq, wqkv_b, D_MODEL * D_MODEL / 8, QSCALE);
  cvt_kernel<<<1024, 256, 0, stream>>>(Wk, wqkv_b + (size_t)D_MODEL * D_MODEL, D_MODEL * D_MODEL / 8, 1.0f);
  cvt_kernel<<<1024, 256, 0, stream>>>(Wv, wqkv_b + (size_t)2 * D_MODEL * D_MODEL, D_MODEL * D_MODEL / 8, 1.0f);
  cvt_kernel<<<1024, 256, 0, stream>>>(Wo, wo_b, D_MODEL * D_MODEL / 8, 1.0f);
  cvt_w1p_kernel<<<2048, 256, 0, stream>>>(W1, w1_b);
  cvt_kernel<<<2048, 256, 0, stream>>>(W2, w2_b, D_MODEL * D_FF / 8, 1.0f);
  biasqkv_kernel<<<QKV_LD / 256, 256, 0, stream>>>(bq, bk, bv, rot, biasq);
  permb1_kernel<<<2 * D_FF / 256, 256, 0, stream>>>(b1, b1p);

  // norm1 -> h
  rmsnorm_kernel<<<M_TOK, 256, 0, stream>>>(x, n1w, h_b);

  // fused QKV projection (2-phase 256^2, 32x32 MFMA); grid = (N-tiles, M-tiles)
  gemm_p8<0><<<dim3(QKV_LD / 256, M_TOK / 256), 512, 0, stream>>>(
      h_b, D_MODEL, wqkv_b, D_MODEL, biasq, qkv_b, QKV_LD, D_MODEL, 0);

  // V transpose + attention
  vtrans_kernel<<<dim3(SEQ / 32, BATCH * N_HEADS), 256, 0, stream>>>(qkv_b, vt_b);
  attn_kernel<<<dim3(SEQ / 256, BATCH * N_HEADS), 512, 0, stream>>>(qkv_b, vt_b, o_b);

  // O projection + residual -> d_out (f32), 128^2 structure
  gemm_bt<1><<<dim3(D_MODEL / 128, M_TOK / 128), 256, 0, stream>>>(
      o_b, D_MODEL, wo_b, D_MODEL, bo, x, out, D_MODEL, D_MODEL, 0);

  // norm2 -> h2
  rmsnorm_kernel<<<M_TOK, 256, 0, stream>>>(out, n2w, h2_b);

  // W1 + fused SwiGLU -> ff (2-phase 256^2, MODE 3)
  gemm_p8<3><<<dim3(2 * D_FF / 256, M_TOK / 256), 512, 0, stream>>>(
      h2_b, D_MODEL, w1_b, D_MODEL, b1p, ff_b, 2 * D_FF, D_MODEL, 0);

  // W2 split-K on gemm_p8 (z=2): A = ff [4096][8192]
  gemm_p8<2><<<dim3(D_MODEL / 256, M_TOK / 256, 2), 512, 0, stream>>>(
      ff_b, D_FF, w2_b, D_FF, nullptr, p0, D_MODEL, D_FF / 2,
      (size_t)M_TOK * D_MODEL);

  // out += p0 + p1 + b2
  reduce2_kernel<<<(M_TOK * D_MODEL / 4) / 256, 256, 0, stream>>>(p0, p1, b2, out);
}

// Round 13
// 877.817 us; speedup vs baseline: 1.0593x; 1.0428x over previous
//
#include <hip/hip_runtime.h>
#include <hip/hip_bf16.h>

#define D_MODEL 2048
#define N_HEADS 16
#define HEAD_DIM 128
#define D_FF 8192
#define BATCH 2
#define SEQ 2048
#define M_TOK (BATCH * SEQ)
#define QKV_LD 6144
// 1/sqrt(128) * log2(e): folded into Wq/bq so scores are in exp2 domain
#define QSCALE 0.12751744f

typedef __attribute__((ext_vector_type(8))) short short8;
typedef __attribute__((ext_vector_type(4))) short short4v;
typedef __attribute__((ext_vector_type(4))) float f32x4;
typedef __attribute__((ext_vector_type(16))) float f32x16;
typedef __attribute__((ext_vector_type(2))) unsigned int uint2v;
typedef __attribute__((ext_vector_type(4))) unsigned int uint4v;

__device__ __forceinline__ unsigned short f2b(float f) {
  __hip_bfloat16 h = __float2bfloat16(f);
  return *reinterpret_cast<unsigned short*>(&h);
}
__device__ __forceinline__ float b2f(unsigned short u) {
  unsigned int x = ((unsigned int)u) << 16;
  return __uint_as_float(x);
}

__device__ __forceinline__ void gload_lds16(const void* gsrc, void* ldst) {
  __builtin_amdgcn_global_load_lds(
      (const __attribute__((address_space(1))) void*)gsrc,
      (__attribute__((address_space(3))) void*)ldst, 16, 0, 0);
}

__device__ __forceinline__ f32x16 mfma32(short8 a, short8 b, f32x16 c) {
  return __builtin_amdgcn_mfma_f32_32x32x16_bf16(a, b, c, 0, 0, 0);
}
__device__ __forceinline__ unsigned int cvtpk(float lo, float hi) {
  unsigned int r;
  asm("v_cvt_pk_bf16_f32 %0, %1, %2" : "=v"(r) : "v"(lo), "v"(hi));
  return r;
}
__device__ __forceinline__ uint2v plswap(unsigned int a, unsigned int b) {
  return __builtin_amdgcn_permlane32_swap(a, b, false, false);
}

// ---------------- f32 -> bf16 convert (optional scale) -----------------------
__global__ __launch_bounds__(256)
void cvt_kernel(const float* __restrict__ src, unsigned short* __restrict__ dst,
                int nchunks, float scale) {
  int i = blockIdx.x * blockDim.x + threadIdx.x;
  int stride = gridDim.x * blockDim.x;
  for (int c = i; c < nchunks; c += stride) {
    const float4 a = *(const float4*)(src + (size_t)c * 8);
    const float4 b = *(const float4*)(src + (size_t)c * 8 + 4);
    short8 r;
    r[0] = f2b(a.x * scale); r[1] = f2b(a.y * scale);
    r[2] = f2b(a.z * scale); r[3] = f2b(a.w * scale);
    r[4] = f2b(b.x * scale); r[5] = f2b(b.y * scale);
    r[6] = f2b(b.z * scale); r[7] = f2b(b.w * scale);
    *(short8*)(dst + (size_t)c * 8) = r;
  }
}

// ---------------- W1 -> bf16 with row interleave -----------------------------
__global__ __launch_bounds__(256)
void cvt_w1p_kernel(const float* __restrict__ src,
                    unsigned short* __restrict__ dst) {
  int i = blockIdx.x * blockDim.x + threadIdx.x;
  int stride = gridDim.x * blockDim.x;
  const int total = 2 * D_FF * (D_MODEL / 8);
  for (int c = i; c < total; c += stride) {
    int rp = c >> 8, col8 = c & 255;
    int b = rp >> 6, half = (rp >> 5) & 1;
    int rs = half * D_FF + b * 32 + (rp & 31);
    const float* s = src + (size_t)rs * D_MODEL + col8 * 8;
    const float4 a = *(const float4*)s;
    const float4 bb = *(const float4*)(s + 4);
    short8 r;
    r[0] = f2b(a.x); r[1] = f2b(a.y); r[2] = f2b(a.z); r[3] = f2b(a.w);
    r[4] = f2b(bb.x); r[5] = f2b(bb.y); r[6] = f2b(bb.z); r[7] = f2b(bb.w);
    *(short8*)(dst + (size_t)c * 8) = r;
  }
}

// ---------------- b1 permuted to match W1' row order -------------------------
__global__ void permb1_kernel(const float* __restrict__ b1,
                              float* __restrict__ b1p) {
  int i = blockIdx.x * 256 + threadIdx.x;
  int b = i >> 6, half = (i >> 5) & 1;
  b1p[i] = b1[half * D_FF + b * 32 + (i & 31)];
}

// ---------------- concat bias: [(bq+rot)*QSCALE | bk | bv] -------------------
__global__ void biasqkv_kernel(const float* __restrict__ bq,
                               const float* __restrict__ bk,
                               const float* __restrict__ bv,
                               const float* __restrict__ rot,
                               float* __restrict__ outp) {
  int i = blockIdx.x * 256 + threadIdx.x;
  float v;
  if (i < 2048) v = (bq[i] + rot[i & (HEAD_DIM - 1)]) * QSCALE;
  else if (i < 4096) v = bk[i - 2048];
  else v = bv[i - 4096];
  outp[i] = v;
}

// ---------------- RMSNorm: f32 in -> bf16 out --------------------------------
__global__ __launch_bounds__(256)
void rmsnorm_kernel(const float* __restrict__ x, const float* __restrict__ wv,
                    unsigned short* __restrict__ outp) {
  const int row = blockIdx.x;
  const float* xr = x + (size_t)row * D_MODEL;
  const int base = threadIdx.x * 8;
  float4 a = *(const float4*)(xr + base);
  float4 c = *(const float4*)(xr + base + 4);
  float ss = a.x * a.x + a.y * a.y + a.z * a.z + a.w * a.w +
             c.x * c.x + c.y * c.y + c.z * c.z + c.w * c.w;
#pragma unroll
  for (int m = 1; m < 64; m <<= 1) ss += __shfl_xor(ss, m);
  __shared__ float red[4];
  if ((threadIdx.x & 63) == 0) red[threadIdx.x >> 6] = ss;
  __syncthreads();
  float tot = red[0] + red[1] + red[2] + red[3];
  float sc = rsqrtf(tot * (1.0f / D_MODEL) + 1e-8f);
  float4 w0 = *(const float4*)(wv + base);
  float4 w1 = *(const float4*)(wv + base + 4);
  short8 r;
  r[0] = f2b(a.x * sc * w0.x); r[1] = f2b(a.y * sc * w0.y);
  r[2] = f2b(a.z * sc * w0.z); r[3] = f2b(a.w * sc * w0.w);
  r[4] = f2b(c.x * sc * w1.x); r[5] = f2b(c.y * sc * w1.y);
  r[6] = f2b(c.z * sc * w1.z); r[7] = f2b(c.w * sc * w1.w);
  *(short8*)(outp + (size_t)row * D_MODEL + base) = r;
}

// ===== GEMM 256x256, BK=64, 2-phase/K-tile pipelined, 32x32x16 MFMA ==========
// Grid: (x = N-tiles, y = M-tiles). r8 swizzle (row&7)<<4 both-sides (rule 21).
// Phase p of a K-tile reads A-half p; B cached in regs from phase 0; 16 MFMA
// per barrier window; vmcnt(4) once per K-tile.
// MODE 0: bf16 out + bias.  MODE 2: f32 partial out (+z*out_zstride).
// MODE 3: swiglu-fused bf16 out (W1': cb0 = x1, cb1 = x2; out LD = N/2).
template <int MODE>
__global__ __launch_bounds__(512, 2)
void gemm_p8(const unsigned short* __restrict__ A, int lda,
             const unsigned short* __restrict__ W, int ldw,
             const float* __restrict__ bias, void* __restrict__ outp,
             int N, int K, size_t out_zstride) {
  __shared__ unsigned short AL[2][2][128 * 64];
  __shared__ unsigned short BL[2][2][128 * 64];
  const int t = threadIdx.x;
  const int l = t & 63, w = t >> 6;
  const int wm = w >> 2, wn = w & 3;
  const int ln = l & 31, hi = l >> 5;
  const int m0 = blockIdx.y << 8, n0 = blockIdx.x << 8;
  const int koff = blockIdx.z * K;

  const int r0 = t >> 3;
  const int cb16 = (t & 7) * 16;
  const int sel = ((cb16 ^ ((r0 & 7) << 4)) >> 1);
  const unsigned short* Abase = A + (size_t)m0 * lda + koff;
  const unsigned short* Wbase = W + (size_t)n0 * ldw + koff;
  const int d0e = t * 8, d1e = (t + 512) * 8;

#define STAGE(XL, Xb, ld, dd, h, ktd)                                        \
  do {                                                                       \
    const unsigned short* s_ =                                               \
        (Xb) + (size_t)((h) * 128 + r0) * (ld) + (ktd) * 64 + sel;           \
    gload_lds16(s_, &XL[dd][h][d0e]);                                        \
    gload_lds16(s_ + (size_t)64 * (ld), &XL[dd][h][d1e]);                    \
  } while (0)

  const int swz = (ln & 7) << 4;
  const int hb = wn >> 1;
  const int browb = ((wn & 1) * 64 + ln) * 128;

  f32x16 acc[4][2] = {};
  short8 bf[2][4];

#define READB(dd)                                                            \
  do {                                                                       \
    const char* Bb_ = (const char*)&BL[dd][hb][0];                           \
    _Pragma("unroll") for (int cb_ = 0; cb_ < 2; cb_++)                      \
      _Pragma("unroll") for (int ks_ = 0; ks_ < 4; ks_++)                    \
        bf[cb_][ks_] = *(const short8*)(Bb_ + browb + cb_ * 4096 +           \
                                        ((ks_ * 32 + hi * 16) ^ swz));       \
  } while (0)

#define PHASE2(dd, p, STAGE_STMT, VM_STMT)                                   \
  do {                                                                       \
    const char* Ab_ = (const char*)&AL[dd][p][0];                            \
    short8 af_[2][4];                                                        \
    if ((p) == 0) READB(dd);                                                 \
    _Pragma("unroll") for (int sb_ = 0; sb_ < 2; sb_++) {                    \
      _Pragma("unroll") for (int ks_ = 0; ks_ < 4; ks_++)                    \
        af_[sb_][ks_] = *(const short8*)(Ab_ +                               \
                                         (wm * 64 + sb_ * 32 + ln) * 128 +   \
                                         ((ks_ * 32 + hi * 16) ^ swz));      \
    }                                                                        \
    STAGE_STMT;                                                              \
    __builtin_amdgcn_sched_barrier(0);                                       \
    VM_STMT;                                                                 \
    __builtin_amdgcn_sched_barrier(0);                                       \
    __builtin_amdgcn_s_barrier();                                            \
    __builtin_amdgcn_sched_barrier(0);                                       \
    __builtin_amdgcn_s_setprio(1);                                           \
    _Pragma("unroll") for (int sb_ = 0; sb_ < 2; sb_++)                      \
      _Pragma("unroll") for (int cb_ = 0; cb_ < 2; cb_++)                    \
        _Pragma("unroll") for (int ks_ = 0; ks_ < 4; ks_++)                  \
          acc[2 * (p) + sb_][cb_] =                                          \
              mfma32(af_[sb_][ks_], bf[cb_][ks_], acc[2 * (p) + sb_][cb_]);  \
    __builtin_amdgcn_s_setprio(0);                                           \
    __builtin_amdgcn_sched_barrier(0);                                       \
    __builtin_amdgcn_s_barrier();                                            \
    __builtin_amdgcn_sched_barrier(0);                                       \
  } while (0)

  const int NT = K >> 6;

  STAGE(AL, Abase, lda, 0, 0, 0);
  STAGE(AL, Abase, lda, 0, 1, 0);
  STAGE(BL, Wbase, ldw, 0, 0, 0);
  STAGE(BL, Wbase, ldw, 0, 1, 0);
  STAGE(AL, Abase, lda, 1, 0, 1);
  STAGE(BL, Wbase, ldw, 1, 0, 1);
  asm volatile("s_waitcnt vmcnt(4)" ::: "memory");
  __builtin_amdgcn_sched_barrier(0);
  __builtin_amdgcn_s_barrier();
  __builtin_amdgcn_sched_barrier(0);

  for (int kt = 0; kt < NT; kt += 2) {
    PHASE2(0, 0,
           {
             if (kt + 1 < NT) {
               STAGE(BL, Wbase, ldw, 1, 1, kt + 1);
               STAGE(AL, Abase, lda, 1, 1, kt + 1);
             }
           },
           {});
    PHASE2(0, 1,
           {
             if (kt + 2 < NT) {
               STAGE(AL, Abase, lda, 0, 0, kt + 2);
               STAGE(BL, Wbase, ldw, 0, 0, kt + 2);
             }
           },
           {
             if (kt + 2 < NT)
               asm volatile("s_waitcnt vmcnt(4)" ::: "memory");
             else
               asm volatile("s_waitcnt vmcnt(0)" ::: "memory");
           });
    PHASE2(1, 0,
           {
             if (kt + 2 < NT) {
               STAGE(BL, Wbase, ldw, 0, 1, kt + 2);
               STAGE(AL, Abase, lda, 0, 1, kt + 2);
             }
           },
           {});
    PHASE2(1, 1,
           {
             if (kt + 3 < NT) {
               STAGE(AL, Abase, lda, 1, 0, kt + 3);
               STAGE(BL, Wbase, ldw, 1, 0, kt + 3);
             }
           },
           {
             if (kt + 3 < NT)
               asm volatile("s_waitcnt vmcnt(4)" ::: "memory");
             else
               asm volatile("s_waitcnt vmcnt(0)" ::: "memory");
           });
  }
#undef PHASE2
#undef READB
#undef STAGE

  // epilogue: row = m0+(rb>>1)*128+wm*64+(rb&1)*32+(r&3)+8*(r>>2)+4*hi
#pragma unroll
  for (int rb = 0; rb < 4; rb++) {
    const int rowb = m0 + (rb >> 1) * 128 + wm * 64 + (rb & 1) * 32 + 4 * hi;
    if (MODE == 3) {
      const int col0 = n0 + wn * 64 + ln;
      const float b1v = bias[col0];
      const float b2v = bias[col0 + 32];
      const int jout = (n0 >> 1) + wn * 32 + ln;
#pragma unroll
      for (int r = 0; r < 16; r++) {
        const int row = rowb + (r & 3) + 8 * (r >> 2);
        float x1 = acc[rb][0][r] + b1v;
        float x2 = acc[rb][1][r] + b2v;
        // silu via fast rcp (bf16 output tolerates approx)
        float sg = x2 * __builtin_amdgcn_rcpf(1.0f + __expf(-x2));
        ((unsigned short*)outp)[(size_t)row * (N >> 1) + jout] = f2b(x1 * sg);
      }
    } else {
#pragma unroll
      for (int cb = 0; cb < 2; cb++) {
        const int col = n0 + wn * 64 + cb * 32 + ln;
        const float bv = (MODE == 0) ? bias[col] : 0.0f;
#pragma unroll
        for (int r = 0; r < 16; r++) {
          const int row = rowb + (r & 3) + 8 * (r >> 2);
          const float vv = acc[rb][cb][r] + bv;
          if (MODE == 0)
            ((unsigned short*)outp)[(size_t)row * N + col] = f2b(vv);
          else
            ((float*)outp + blockIdx.z * out_zstride)[(size_t)row * N + col] = vv;
        }
      }
    }
  }
}

// ---------------- V transpose: qkv v-slice -> vt[(bh*128+d)*S + s] -----------
__global__ __launch_bounds__(256)
void vtrans_kernel(const unsigned short* __restrict__ qkv,
                   unsigned short* __restrict__ vt) {
  const int bh = blockIdx.y;
  const int b = bh >> 4, h = bh & 15;
  const int s0 = blockIdx.x * 32;
  __shared__ unsigned short tile[32][136];
  const int t = threadIdx.x;
  for (int i = 0; i < 2; i++) {
    int c = t + i * 256;
    int s = c >> 4, dc = c & 15;
    *(short8*)&tile[s][dc * 8] =
        *(const short8*)(qkv + (size_t)(b * SEQ + s0 + s) * QKV_LD + 4096 +
                         h * HEAD_DIM + dc * 8);
  }
  __syncthreads();
  const int d = t >> 1, sh = (t & 1) * 16;
  unsigned short* dst = vt + ((size_t)bh * HEAD_DIM + d) * SEQ + s0 + sh;
  short8 r0, r1;
#pragma unroll
  for (int j = 0; j < 8; j++) r0[j] = tile[sh + j][d];
#pragma unroll
  for (int j = 0; j < 8; j++) r1[j] = tile[sh + 8 + j][d];
  *(short8*)dst = r0;
  *(short8*)(dst + 8) = r1;
}

// ======== Flash attention: 8-warp 32x32 swapped-operand (T5 setprio) =========
__global__ __launch_bounds__(512, 2)
void attn_kernel(const unsigned short* __restrict__ qkv,
                 const unsigned short* __restrict__ vt,
                 unsigned short* __restrict__ o) {
  const int bh = blockIdx.y;
  const int b = bh >> 4, h = bh & 15;
  const int q0 = blockIdx.x << 8;
  const int t = threadIdx.x, w = t >> 6, l = t & 63;
  const int ln = l & 31, hi = l >> 5;

  __shared__ unsigned short Ks[2][64 * 128];

  short8 qf[8];
  {
    const unsigned short* qb =
        qkv + (size_t)(b * SEQ + q0 + w * 32 + ln) * QKV_LD + h * HEAD_DIM +
        hi * 8;
#pragma unroll
    for (int sl = 0; sl < 8; sl++) qf[sl] = *(const short8*)(qb + sl * 16);
  }

  f32x16 oacc[4] = {};
  float mrow = -1e30f, lrow = 0.f;

  const unsigned short* kbase =
      qkv + (size_t)(b * SEQ) * QKV_LD + 2048 + h * HEAD_DIM;
  const unsigned short* vbase = vt + (size_t)bh * HEAD_DIM * SEQ;

#define STAGEK(buf, kv0_)                                                    \
  do {                                                                       \
    _Pragma("unroll") for (int i_ = 0; i_ < 2; i_++) {                       \
      int c_ = t + i_ * 512;                                                 \
      int row_ = c_ >> 4, dc_ = c_ & 15;                                     \
      int sel_ = ((dc_ * 16) ^ ((row_ & 7) << 4)) >> 1;                      \
      gload_lds16(kbase + (size_t)((kv0_) + row_) * QKV_LD + sel_,           \
                  &Ks[buf][c_ * 8]);                                         \
    }                                                                        \
  } while (0)

  STAGEK(0, 0);
  __syncthreads();

  for (int it = 0; it < SEQ / 64; ++it) {
    const int cur = it & 1;
    const int kv0 = it * 64;

    short8 vf[4][4];
#pragma unroll
    for (int db = 0; db < 4; db++)
#pragma unroll
      for (int ks = 0; ks < 4; ks++)
        vf[db][ks] = *(const short8*)(vbase + (size_t)(db * 32 + ln) * SEQ +
                                      kv0 + ks * 16 + hi * 8);

    if (it + 1 < SEQ / 64) STAGEK(cur ^ 1, kv0 + 64);

    const char* kb = (const char*)&Ks[cur][0];
    f32x16 s0 = {}, s1 = {};
    __builtin_amdgcn_s_setprio(1);
#pragma unroll
    for (int sl = 0; sl < 8; sl++) {
      const int cw = (sl * 32 + hi * 16) ^ ((ln & 7) << 4);
      short8 kf0 = *(const short8*)(kb + ln * 256 + cw);
      short8 kf1 = *(const short8*)(kb + (32 + ln) * 256 + cw);
      s0 = mfma32(kf0, qf[sl], s0);
      s1 = mfma32(kf1, qf[sl], s1);
    }
    __builtin_amdgcn_s_setprio(0);

    float mx = s0[0];
#pragma unroll
    for (int r = 1; r < 16; r++) mx = fmaxf(mx, s0[r]);
#pragma unroll
    for (int r = 0; r < 16; r++) mx = fmaxf(mx, s1[r]);
    {
      uint2v r2 = plswap(__float_as_uint(mx), __float_as_uint(mx));
      mx = fmaxf(__uint_as_float(r2[0]), __uint_as_float(r2[1]));
    }

    if (!__all(mx <= mrow + 8.f)) {
      float mnew = fmaxf(mrow, mx);
      float fs = exp2f(mrow - mnew);
      mrow = mnew;
      lrow *= fs;
#pragma unroll
      for (int db = 0; db < 4; db++)
#pragma unroll
        for (int r = 0; r < 16; r++) oacc[db][r] *= fs;
    }

    float p0[16], p1[16];
    float sum = 0.f;
#pragma unroll
    for (int r = 0; r < 16; r++) {
      p0[r] = exp2f(s0[r] - mrow);
      sum += p0[r];
    }
#pragma unroll
    for (int r = 0; r < 16; r++) {
      p1[r] = exp2f(s1[r] - mrow);
      sum += p1[r];
    }
    lrow += sum;

    uint4v pk[4];
#define PACKSUB(P, K0)                                                       \
  {                                                                          \
    unsigned int a_, b_;                                                     \
    uint2v r_;                                                               \
    a_ = cvtpk(P[0], P[1]); b_ = cvtpk(P[4], P[5]);                          \
    r_ = plswap(a_, b_); pk[K0][0] = r_[0]; pk[K0][2] = r_[1];               \
    a_ = cvtpk(P[2], P[3]); b_ = cvtpk(P[6], P[7]);                          \
    r_ = plswap(a_, b_); pk[K0][1] = r_[0]; pk[K0][3] = r_[1];               \
    a_ = cvtpk(P[8], P[9]); b_ = cvtpk(P[12], P[13]);                        \
    r_ = plswap(a_, b_); pk[K0 + 1][0] = r_[0]; pk[K0 + 1][2] = r_[1];       \
    a_ = cvtpk(P[10], P[11]); b_ = cvtpk(P[14], P[15]);                      \
    r_ = plswap(a_, b_); pk[K0 + 1][1] = r_[0]; pk[K0 + 1][3] = r_[1];       \
  }
    PACKSUB(p0, 0);
    PACKSUB(p1, 2);
#undef PACKSUB

    __builtin_amdgcn_s_setprio(1);
#pragma unroll
    for (int db = 0; db < 4; db++)
#pragma unroll
      for (int ks = 0; ks < 4; ks++)
        oacc[db] = mfma32(vf[db][ks], __builtin_bit_cast(short8, pk[ks]),
                          oacc[db]);
    __builtin_amdgcn_s_setprio(0);

    __syncthreads();
  }
#undef STAGEK

  {
    uint2v r2 = plswap(__float_as_uint(lrow), __float_as_uint(lrow));
    lrow = __uint_as_float(r2[0]) + __uint_as_float(r2[1]);
  }
  const float inv = 1.0f / lrow;
  unsigned short* ob = o + (size_t)(b * SEQ + q0 + w * 32 + ln) * D_MODEL +
                       h * HEAD_DIM + hi * 4;
#pragma unroll
  for (int db = 0; db < 4; db++)
#pragma unroll
    for (int r = 0; r < 4; r++) {
      short4v v4;
#pragma unroll
      for (int j = 0; j < 4; j++)
        v4[j] = (short)f2b(oacc[db][4 * r + j] * inv);
      *(short4v*)(ob + db * 32 + r * 8) = v4;
    }
}

// ---------------- O-proj reduce: out = p0 + p1 + bo + x ----------------------
__global__ __launch_bounds__(256)
void reduceo_kernel(const float* __restrict__ p0, const float* __restrict__ p1,
                    const float* __restrict__ bo, const float* __restrict__ x,
                    float* __restrict__ out) {
  size_t i = (size_t)blockIdx.x * 256 + threadIdx.x;
  float4 a = ((const float4*)p0)[i];
  float4 b = ((const float4*)p1)[i];
  float4 xx = ((const float4*)x)[i];
  float4 bb = ((const float4*)bo)[i & 511];
  float4 o;
  o.x = a.x + b.x + xx.x + bb.x;
  o.y = a.y + b.y + xx.y + bb.y;
  o.z = a.z + b.z + xx.z + bb.z;
  o.w = a.w + b.w + xx.w + bb.w;
  ((float4*)out)[i] = o;
}

// ---------------- split-K reduce: out += p0 + p1 + b2 ------------------------
__global__ __launch_bounds__(256)
void reduce2_kernel(const float* __restrict__ p0, const float* __restrict__ p1,
                    const float* __restrict__ b2, float* __restrict__ out) {
  size_t i = (size_t)blockIdx.x * 256 + threadIdx.x;
  float4 a = ((const float4*)p0)[i];
  float4 b = ((const float4*)p1)[i];
  float4 o = ((const float4*)out)[i];
  float4 bb = ((const float4*)b2)[i & 511];
  o.x += a.x + b.x + bb.x;
  o.y += a.y + b.y + bb.y;
  o.z += a.z + b.z + bb.z;
  o.w += a.w + b.w + bb.w;
  ((float4*)out)[i] = o;
}

// ---------------- host: launch sequence --------------------------------------
extern "C" void kernel_launch(void* const* d_in, const int* in_sizes, int n_in,
                              void* d_out, int out_size, void* d_ws,
                              size_t ws_size, hipStream_t stream) {
  (void)in_sizes; (void)n_in; (void)out_size; (void)ws_size;
  const float* x   = (const float*)d_in[0];
  const float* Wq  = (const float*)d_in[1];
  const float* bq  = (const float*)d_in[2];
  const float* Wk  = (const float*)d_in[3];
  const float* bk  = (const float*)d_in[4];
  const float* Wv  = (const float*)d_in[5];
  const float* bv  = (const float*)d_in[6];
  const float* Wo  = (const float*)d_in[7];
  const float* bo  = (const float*)d_in[8];
  const float* rot = (const float*)d_in[9];
  const float* n1w = (const float*)d_in[10];
  const float* n2w = (const float*)d_in[11];
  const float* W1  = (const float*)d_in[12];
  const float* b1  = (const float*)d_in[13];
  const float* W2  = (const float*)d_in[14];
  const float* b2  = (const float*)d_in[15];
  float* out = (float*)d_out;
  char* ws = (char*)d_ws;

  const size_t SZ_D2  = (size_t)D_MODEL * D_MODEL * 2;   // 8 MiB
  const size_t SZ_ACT = (size_t)M_TOK * D_MODEL * 2;     // 16 MiB
  const size_t SZ_W1  = (size_t)2 * D_FF * D_MODEL * 2;  // 64 MiB
  const size_t SZ_W2  = (size_t)D_MODEL * D_FF * 2;      // 32 MiB
  const size_t SZ_G   = (size_t)M_TOK * 2 * D_FF * 2;    // 128 MiB

  size_t off = 0;
  auto alloc = [&](size_t sz) { size_t o = off; off += (sz + 255) & ~(size_t)255; return o; };
  unsigned short* wqkv_b = (unsigned short*)(ws + alloc(3 * SZ_D2));  // at ws+0
  unsigned short* wo_b   = (unsigned short*)(ws + alloc(SZ_D2));
  unsigned short* w1_b   = (unsigned short*)(ws + alloc(SZ_W1));     // permuted W1'
  unsigned short* w2_b   = (unsigned short*)(ws + alloc(SZ_W2));
  float*          biasq  = (float*)(ws + alloc(QKV_LD * 4));
  float*          b1p    = (float*)(ws + alloc(2 * D_FF * 4));
  unsigned short* h2_b   = (unsigned short*)(ws + alloc(SZ_ACT));
  char* pool = ws + alloc(SZ_G);
  // phase 1 overlay in pool: h | qkv | vt | o   (16+48+16+16 = 96 MiB)
  unsigned short* h_b   = (unsigned short*)(pool);
  unsigned short* qkv_b = (unsigned short*)(pool + SZ_ACT);
  unsigned short* vt_b  = (unsigned short*)(pool + 4 * SZ_ACT);
  unsigned short* o_b   = (unsigned short*)(pool + 5 * SZ_ACT);
  // O-proj partials: overlay the then-dead h|qkv region (pool+0 .. +67 MiB);
  // o_b at pool+80 MiB stays live.
  float* po0 = (float*)pool;
  float* po1 = po0 + (size_t)M_TOK * D_MODEL;
  // phase 2 overlay: ff (4096 x 8192 bf16 = 64 MiB) occupies pool start
  unsigned short* ff_b  = (unsigned short*)(pool);
  // W2 split-K partials overlay the (then-dead) wqkv/wo/w1 region
  float* p0 = (float*)ws;
  float* p1 = p0 + (size_t)M_TOK * D_MODEL;

  // weights -> bf16 (Q,K,V concatenated row-wise; Wq pre-scaled by QSCALE)
  cvt_kernel<<<1024, 256, 0, stream>>>(Wq, wqkv_b, D_MODEL * D_MODEL / 8, QSCALE);
  cvt_kernel<<<1024, 256, 0, stream>>>(Wk, wqkv_b + (size_t)D_MODEL * D_MODEL, D_MODEL * D_MODEL / 8, 1.0f);
  cvt_kernel<<<1024, 256, 0, stream>>>(Wv, wqkv_b + (size_t)2 * D_MODEL * D_MODEL, D_MODEL * D_MODEL / 8, 1.0f);
  cvt_kernel<<<1024, 256, 0, stream>>>(Wo, wo_b, D_MODEL * D_MODEL / 8, 1.0f);
  cvt_w1p_kernel<<<2048, 256, 0, stream>>>(W1, w1_b);
  cvt_kernel<<<2048, 256, 0, stream>>>(W2, w2_b, D_MODEL * D_FF / 8, 1.0f);
  biasqkv_kernel<<<QKV_LD / 256, 256, 0, stream>>>(bq, bk, bv, rot, biasq);
  permb1_kernel<<<2 * D_FF / 256, 256, 0, stream>>>(b1, b1p);

  // norm1 -> h
  rmsnorm_kernel<<<M_TOK, 256, 0, stream>>>(x, n1w, h_b);

  // fused QKV projection (2-phase 256^2, 32x32 MFMA)
  gemm_p8<0><<<dim3(QKV_LD / 256, M_TOK / 256), 512, 0, stream>>>(
      h_b, D_MODEL, wqkv_b, D_MODEL, biasq, qkv_b, QKV_LD, D_MODEL, 0);

  // V transpose + attention
  vtrans_kernel<<<dim3(SEQ / 32, BATCH * N_HEADS), 256, 0, stream>>>(qkv_b, vt_b);
  attn_kernel<<<dim3(SEQ / 256, BATCH * N_HEADS), 512, 0, stream>>>(qkv_b, vt_b, o_b);

  // O projection split-K (z=2, K=1024 each) -> po0/po1, then fused reduce
  gemm_p8<2><<<dim3(D_MODEL / 256, M_TOK / 256, 2), 512, 0, stream>>>(
      o_b, D_MODEL, wo_b, D_MODEL, nullptr, po0, D_MODEL, D_MODEL / 2,
      (size_t)M_TOK * D_MODEL);
  reduceo_kernel<<<(M_TOK * D_MODEL / 4) / 256, 256, 0, stream>>>(
      po0, po1, bo, x, out);

  // norm2 -> h2
  rmsnorm_kernel<<<M_TOK, 256, 0, stream>>>(out, n2w, h2_b);

  // W1 + fused SwiGLU -> ff (2-phase 256^2, MODE 3)
  gemm_p8<3><<<dim3(2 * D_FF / 256, M_TOK / 256), 512, 0, stream>>>(
      h2_b, D_MODEL, w1_b, D_MODEL, b1p, ff_b, 2 * D_FF, D_MODEL, 0);

  // W2 split-K on gemm_p8 (z=2): A = ff [4096][8192]
  gemm_p8<2><<<dim3(D_MODEL / 256, M_TOK / 256, 2), 512, 0, stream>>>(
      ff_b, D_FF, w2_b, D_FF, nullptr, p0, D_MODEL, D_FF / 2,
      (size_t)M_TOK * D_MODEL);

  // out += p0 + p1 + b2
  reduce2_kernel<<<(M_TOK * D_MODEL / 4) / 256, 256, 0, stream>>>(p0, p1, b2, out);
}

// Round 14
// 852.039 us; speedup vs baseline: 1.0913x; 1.0303x over previous
//
#include <hip/hip_runtime.h>
#include <hip/hip_bf16.h>

#define D_MODEL 2048
#define N_HEADS 16
#define HEAD_DIM 128
#define D_FF 8192
#define BATCH 2
#define SEQ 2048
#define M_TOK (BATCH * SEQ)
#define QKV_LD 6144
// 1/sqrt(128) * log2(e): folded into Wq/bq so scores are in exp2 domain
#define QSCALE 0.12751744f

typedef __attribute__((ext_vector_type(8))) short short8;
typedef __attribute__((ext_vector_type(4))) short short4v;
typedef __attribute__((ext_vector_type(4))) float f32x4;
typedef __attribute__((ext_vector_type(16))) float f32x16;
typedef __attribute__((ext_vector_type(2))) unsigned int uint2v;
typedef __attribute__((ext_vector_type(4))) unsigned int uint4v;

__device__ __forceinline__ unsigned short f2b(float f) {
  __hip_bfloat16 h = __float2bfloat16(f);
  return *reinterpret_cast<unsigned short*>(&h);
}
__device__ __forceinline__ float b2f(unsigned short u) {
  unsigned int x = ((unsigned int)u) << 16;
  return __uint_as_float(x);
}

__device__ __forceinline__ void gload_lds16(const void* gsrc, void* ldst) {
  __builtin_amdgcn_global_load_lds(
      (const __attribute__((address_space(1))) void*)gsrc,
      (__attribute__((address_space(3))) void*)ldst, 16, 0, 0);
}

__device__ __forceinline__ f32x16 mfma32(short8 a, short8 b, f32x16 c) {
  return __builtin_amdgcn_mfma_f32_32x32x16_bf16(a, b, c, 0, 0, 0);
}
__device__ __forceinline__ unsigned int cvtpk(float lo, float hi) {
  unsigned int r;
  asm("v_cvt_pk_bf16_f32 %0, %1, %2" : "=v"(r) : "v"(lo), "v"(hi));
  return r;
}
__device__ __forceinline__ uint2v plswap(unsigned int a, unsigned int b) {
  return __builtin_amdgcn_permlane32_swap(a, b, false, false);
}

// ---------------- merged weight convert: Wq(scaled)|Wk|Wv -> wqkv, Wo, W2 ----
__global__ __launch_bounds__(256)
void cvt_all_kernel(const float* __restrict__ Wq, const float* __restrict__ Wk,
                    const float* __restrict__ Wv, const float* __restrict__ Wo,
                    const float* __restrict__ W2w,
                    unsigned short* __restrict__ wqkv,
                    unsigned short* __restrict__ wo,
                    unsigned short* __restrict__ w2) {
  const int NC = (D_MODEL * D_MODEL) / 8;  // 524288 chunks per d^2 matrix
  const int TOT = 4 * NC + (D_MODEL * D_FF) / 8;
  int i = blockIdx.x * 256 + threadIdx.x;
  int stride = gridDim.x * 256;
  for (int c = i; c < TOT; c += stride) {
    const float* s;
    unsigned short* d;
    float sc = 1.0f;
    if (c < NC) { s = Wq + (size_t)c * 8; d = wqkv + (size_t)c * 8; sc = QSCALE; }
    else if (c < 2 * NC) { s = Wk + (size_t)(c - NC) * 8; d = wqkv + (size_t)c * 8; }
    else if (c < 3 * NC) { s = Wv + (size_t)(c - 2 * NC) * 8; d = wqkv + (size_t)c * 8; }
    else if (c < 4 * NC) { s = Wo + (size_t)(c - 3 * NC) * 8; d = wo + (size_t)(c - 3 * NC) * 8; }
    else { s = W2w + (size_t)(c - 4 * NC) * 8; d = w2 + (size_t)(c - 4 * NC) * 8; }
    const float4 a = *(const float4*)s;
    const float4 b = *(const float4*)(s + 4);
    short8 r;
    r[0] = f2b(a.x * sc); r[1] = f2b(a.y * sc);
    r[2] = f2b(a.z * sc); r[3] = f2b(a.w * sc);
    r[4] = f2b(b.x * sc); r[5] = f2b(b.y * sc);
    r[6] = f2b(b.z * sc); r[7] = f2b(b.w * sc);
    *(short8*)d = r;
  }
}

// ---------------- W1 -> bf16 with row interleave -----------------------------
__global__ __launch_bounds__(256)
void cvt_w1p_kernel(const float* __restrict__ src,
                    unsigned short* __restrict__ dst) {
  int i = blockIdx.x * blockDim.x + threadIdx.x;
  int stride = gridDim.x * blockDim.x;
  const int total = 2 * D_FF * (D_MODEL / 8);
  for (int c = i; c < total; c += stride) {
    int rp = c >> 8, col8 = c & 255;
    int b = rp >> 6, half = (rp >> 5) & 1;
    int rs = half * D_FF + b * 32 + (rp & 31);
    const float* s = src + (size_t)rs * D_MODEL + col8 * 8;
    const float4 a = *(const float4*)s;
    const float4 bb = *(const float4*)(s + 4);
    short8 r;
    r[0] = f2b(a.x); r[1] = f2b(a.y); r[2] = f2b(a.z); r[3] = f2b(a.w);
    r[4] = f2b(bb.x); r[5] = f2b(bb.y); r[6] = f2b(bb.z); r[7] = f2b(bb.w);
    *(short8*)(dst + (size_t)c * 8) = r;
  }
}

// ---------------- b1 permuted to match W1' row order -------------------------
__global__ void permb1_kernel(const float* __restrict__ b1,
                              float* __restrict__ b1p) {
  int i = blockIdx.x * 256 + threadIdx.x;
  int b = i >> 6, half = (i >> 5) & 1;
  b1p[i] = b1[half * D_FF + b * 32 + (i & 31)];
}

// ---------------- concat bias: [(bq+rot)*QSCALE | bk | bv] -------------------
__global__ void biasqkv_kernel(const float* __restrict__ bq,
                               const float* __restrict__ bk,
                               const float* __restrict__ bv,
                               const float* __restrict__ rot,
                               float* __restrict__ outp) {
  int i = blockIdx.x * 256 + threadIdx.x;
  float v;
  if (i < 2048) v = (bq[i] + rot[i & (HEAD_DIM - 1)]) * QSCALE;
  else if (i < 4096) v = bk[i - 2048];
  else v = bv[i - 4096];
  outp[i] = v;
}

// ---------------- RMSNorm: f32 in -> bf16 out --------------------------------
__global__ __launch_bounds__(256)
void rmsnorm_kernel(const float* __restrict__ x, const float* __restrict__ wv,
                    unsigned short* __restrict__ outp) {
  const int row = blockIdx.x;
  const float* xr = x + (size_t)row * D_MODEL;
  const int base = threadIdx.x * 8;
  float4 a = *(const float4*)(xr + base);
  float4 c = *(const float4*)(xr + base + 4);
  float ss = a.x * a.x + a.y * a.y + a.z * a.z + a.w * a.w +
             c.x * c.x + c.y * c.y + c.z * c.z + c.w * c.w;
#pragma unroll
  for (int m = 1; m < 64; m <<= 1) ss += __shfl_xor(ss, m);
  __shared__ float red[4];
  if ((threadIdx.x & 63) == 0) red[threadIdx.x >> 6] = ss;
  __syncthreads();
  float tot = red[0] + red[1] + red[2] + red[3];
  float sc = rsqrtf(tot * (1.0f / D_MODEL) + 1e-8f);
  float4 w0 = *(const float4*)(wv + base);
  float4 w1 = *(const float4*)(wv + base + 4);
  short8 r;
  r[0] = f2b(a.x * sc * w0.x); r[1] = f2b(a.y * sc * w0.y);
  r[2] = f2b(a.z * sc * w0.z); r[3] = f2b(a.w * sc * w0.w);
  r[4] = f2b(c.x * sc * w1.x); r[5] = f2b(c.y * sc * w1.y);
  r[6] = f2b(c.z * sc * w1.z); r[7] = f2b(c.w * sc * w1.w);
  *(short8*)(outp + (size_t)row * D_MODEL + base) = r;
}

// ===== GEMM 256x256, BK=64, 2-phase/K-tile pipelined, 32x32x16 MFMA ==========
// Grid: (x = N-tiles, y = M-tiles). r8 swizzle (row&7)<<4 both-sides (rule 21).
// MODE 0: bf16 out + bias.  MODE 2: bf16 partial out (+z*out_zstride).
// MODE 3: swiglu-fused bf16 out (W1': cb0 = x1, cb1 = x2; out LD = N/2).
template <int MODE>
__global__ __launch_bounds__(512, 2)
void gemm_p8(const unsigned short* __restrict__ A, int lda,
             const unsigned short* __restrict__ W, int ldw,
             const float* __restrict__ bias, void* __restrict__ outp,
             int N, int K, size_t out_zstride) {
  __shared__ unsigned short AL[2][2][128 * 64];
  __shared__ unsigned short BL[2][2][128 * 64];
  const int t = threadIdx.x;
  const int l = t & 63, w = t >> 6;
  const int wm = w >> 2, wn = w & 3;
  const int ln = l & 31, hi = l >> 5;
  const int m0 = blockIdx.y << 8, n0 = blockIdx.x << 8;
  const int koff = blockIdx.z * K;

  const int r0 = t >> 3;
  const int cb16 = (t & 7) * 16;
  const int sel = ((cb16 ^ ((r0 & 7) << 4)) >> 1);
  const unsigned short* Abase = A + (size_t)m0 * lda + koff;
  const unsigned short* Wbase = W + (size_t)n0 * ldw + koff;
  const int d0e = t * 8, d1e = (t + 512) * 8;

#define STAGE(XL, Xb, ld, dd, h, ktd)                                        \
  do {                                                                       \
    const unsigned short* s_ =                                               \
        (Xb) + (size_t)((h) * 128 + r0) * (ld) + (ktd) * 64 + sel;           \
    gload_lds16(s_, &XL[dd][h][d0e]);                                        \
    gload_lds16(s_ + (size_t)64 * (ld), &XL[dd][h][d1e]);                    \
  } while (0)

  const int swz = (ln & 7) << 4;
  const int hb = wn >> 1;
  const int browb = ((wn & 1) * 64 + ln) * 128;

  f32x16 acc[4][2] = {};
  short8 bf[2][4];

#define READB(dd)                                                            \
  do {                                                                       \
    const char* Bb_ = (const char*)&BL[dd][hb][0];                           \
    _Pragma("unroll") for (int cb_ = 0; cb_ < 2; cb_++)                      \
      _Pragma("unroll") for (int ks_ = 0; ks_ < 4; ks_++)                    \
        bf[cb_][ks_] = *(const short8*)(Bb_ + browb + cb_ * 4096 +           \
                                        ((ks_ * 32 + hi * 16) ^ swz));       \
  } while (0)

#define PHASE2(dd, p, STAGE_STMT, VM_STMT)                                   \
  do {                                                                       \
    const char* Ab_ = (const char*)&AL[dd][p][0];                            \
    short8 af_[2][4];                                                        \
    if ((p) == 0) READB(dd);                                                 \
    _Pragma("unroll") for (int sb_ = 0; sb_ < 2; sb_++) {                    \
      _Pragma("unroll") for (int ks_ = 0; ks_ < 4; ks_++)                    \
        af_[sb_][ks_] = *(const short8*)(Ab_ +                               \
                                         (wm * 64 + sb_ * 32 + ln) * 128 +   \
                                         ((ks_ * 32 + hi * 16) ^ swz));      \
    }                                                                        \
    STAGE_STMT;                                                              \
    __builtin_amdgcn_sched_barrier(0);                                       \
    VM_STMT;                                                                 \
    __builtin_amdgcn_sched_barrier(0);                                       \
    __builtin_amdgcn_s_barrier();                                            \
    __builtin_amdgcn_sched_barrier(0);                                       \
    __builtin_amdgcn_s_setprio(1);                                           \
    _Pragma("unroll") for (int sb_ = 0; sb_ < 2; sb_++)                      \
      _Pragma("unroll") for (int cb_ = 0; cb_ < 2; cb_++)                    \
        _Pragma("unroll") for (int ks_ = 0; ks_ < 4; ks_++)                  \
          acc[2 * (p) + sb_][cb_] =                                          \
              mfma32(af_[sb_][ks_], bf[cb_][ks_], acc[2 * (p) + sb_][cb_]);  \
    __builtin_amdgcn_s_setprio(0);                                           \
    __builtin_amdgcn_sched_barrier(0);                                       \
    __builtin_amdgcn_s_barrier();                                            \
    __builtin_amdgcn_sched_barrier(0);                                       \
  } while (0)

  const int NT = K >> 6;

  STAGE(AL, Abase, lda, 0, 0, 0);
  STAGE(AL, Abase, lda, 0, 1, 0);
  STAGE(BL, Wbase, ldw, 0, 0, 0);
  STAGE(BL, Wbase, ldw, 0, 1, 0);
  STAGE(AL, Abase, lda, 1, 0, 1);
  STAGE(BL, Wbase, ldw, 1, 0, 1);
  asm volatile("s_waitcnt vmcnt(4)" ::: "memory");
  __builtin_amdgcn_sched_barrier(0);
  __builtin_amdgcn_s_barrier();
  __builtin_amdgcn_sched_barrier(0);

  for (int kt = 0; kt < NT; kt += 2) {
    PHASE2(0, 0,
           {
             if (kt + 1 < NT) {
               STAGE(BL, Wbase, ldw, 1, 1, kt + 1);
               STAGE(AL, Abase, lda, 1, 1, kt + 1);
             }
           },
           {});
    PHASE2(0, 1,
           {
             if (kt + 2 < NT) {
               STAGE(AL, Abase, lda, 0, 0, kt + 2);
               STAGE(BL, Wbase, ldw, 0, 0, kt + 2);
             }
           },
           {
             if (kt + 2 < NT)
               asm volatile("s_waitcnt vmcnt(4)" ::: "memory");
             else
               asm volatile("s_waitcnt vmcnt(0)" ::: "memory");
           });
    PHASE2(1, 0,
           {
             if (kt + 2 < NT) {
               STAGE(BL, Wbase, ldw, 0, 1, kt + 2);
               STAGE(AL, Abase, lda, 0, 1, kt + 2);
             }
           },
           {});
    PHASE2(1, 1,
           {
             if (kt + 3 < NT) {
               STAGE(AL, Abase, lda, 1, 0, kt + 3);
               STAGE(BL, Wbase, ldw, 1, 0, kt + 3);
             }
           },
           {
             if (kt + 3 < NT)
               asm volatile("s_waitcnt vmcnt(4)" ::: "memory");
             else
               asm volatile("s_waitcnt vmcnt(0)" ::: "memory");
           });
  }
#undef PHASE2
#undef READB
#undef STAGE

  // epilogue: row = m0+(rb>>1)*128+wm*64+(rb&1)*32+(r&3)+8*(r>>2)+4*hi
#pragma unroll
  for (int rb = 0; rb < 4; rb++) {
    const int rowb = m0 + (rb >> 1) * 128 + wm * 64 + (rb & 1) * 32 + 4 * hi;
    if (MODE == 3) {
      const int col0 = n0 + wn * 64 + ln;
      const float b1v = bias[col0];
      const float b2v = bias[col0 + 32];
      const int jout = (n0 >> 1) + wn * 32 + ln;
#pragma unroll
      for (int r = 0; r < 16; r++) {
        const int row = rowb + (r & 3) + 8 * (r >> 2);
        float x1 = acc[rb][0][r] + b1v;
        float x2 = acc[rb][1][r] + b2v;
        float sg = x2 * __builtin_amdgcn_rcpf(1.0f + __expf(-x2));
        ((unsigned short*)outp)[(size_t)row * (N >> 1) + jout] = f2b(x1 * sg);
      }
    } else {
#pragma unroll
      for (int cb = 0; cb < 2; cb++) {
        const int col = n0 + wn * 64 + cb * 32 + ln;
        const float bv = (MODE == 0) ? bias[col] : 0.0f;
#pragma unroll
        for (int r = 0; r < 16; r++) {
          const int row = rowb + (r & 3) + 8 * (r >> 2);
          const float vv = acc[rb][cb][r] + bv;
          if (MODE == 0)
            ((unsigned short*)outp)[(size_t)row * N + col] = f2b(vv);
          else  // MODE 2: bf16 partial
            ((unsigned short*)outp + blockIdx.z * out_zstride)
                [(size_t)row * N + col] = f2b(vv);
        }
      }
    }
  }
}

// ---------------- V transpose: qkv v-slice -> vt[(bh*128+d)*S + s] -----------
__global__ __launch_bounds__(256)
void vtrans_kernel(const unsigned short* __restrict__ qkv,
                   unsigned short* __restrict__ vt) {
  const int bh = blockIdx.y;
  const int b = bh >> 4, h = bh & 15;
  const int s0 = blockIdx.x * 32;
  __shared__ unsigned short tile[32][136];
  const int t = threadIdx.x;
  for (int i = 0; i < 2; i++) {
    int c = t + i * 256;
    int s = c >> 4, dc = c & 15;
    *(short8*)&tile[s][dc * 8] =
        *(const short8*)(qkv + (size_t)(b * SEQ + s0 + s) * QKV_LD + 4096 +
                         h * HEAD_DIM + dc * 8);
  }
  __syncthreads();
  const int d = t >> 1, sh = (t & 1) * 16;
  unsigned short* dst = vt + ((size_t)bh * HEAD_DIM + d) * SEQ + s0 + sh;
  short8 r0, r1;
#pragma unroll
  for (int j = 0; j < 8; j++) r0[j] = tile[sh + j][d];
#pragma unroll
  for (int j = 0; j < 8; j++) r1[j] = tile[sh + 8 + j][d];
  *(short8*)dst = r0;
  *(short8*)(dst + 8) = r1;
}

// ======== Flash attention: 8-warp 32x32 swapped-operand (T5 setprio) =========
__global__ __launch_bounds__(512, 2)
void attn_kernel(const unsigned short* __restrict__ qkv,
                 const unsigned short* __restrict__ vt,
                 unsigned short* __restrict__ o) {
  const int bh = blockIdx.y;
  const int b = bh >> 4, h = bh & 15;
  const int q0 = blockIdx.x << 8;
  const int t = threadIdx.x, w = t >> 6, l = t & 63;
  const int ln = l & 31, hi = l >> 5;

  __shared__ unsigned short Ks[2][64 * 128];

  short8 qf[8];
  {
    const unsigned short* qb =
        qkv + (size_t)(b * SEQ + q0 + w * 32 + ln) * QKV_LD + h * HEAD_DIM +
        hi * 8;
#pragma unroll
    for (int sl = 0; sl < 8; sl++) qf[sl] = *(const short8*)(qb + sl * 16);
  }

  f32x16 oacc[4] = {};
  float mrow = -1e30f, lrow = 0.f;

  const unsigned short* kbase =
      qkv + (size_t)(b * SEQ) * QKV_LD + 2048 + h * HEAD_DIM;
  const unsigned short* vbase = vt + (size_t)bh * HEAD_DIM * SEQ;

#define STAGEK(buf, kv0_)                                                    \
  do {                                                                       \
    _Pragma("unroll") for (int i_ = 0; i_ < 2; i_++) {                       \
      int c_ = t + i_ * 512;                                                 \
      int row_ = c_ >> 4, dc_ = c_ & 15;                                     \
      int sel_ = ((dc_ * 16) ^ ((row_ & 7) << 4)) >> 1;                      \
      gload_lds16(kbase + (size_t)((kv0_) + row_) * QKV_LD + sel_,           \
                  &Ks[buf][c_ * 8]);                                         \
    }                                                                        \
  } while (0)

  STAGEK(0, 0);
  __syncthreads();

  for (int it = 0; it < SEQ / 64; ++it) {
    const int cur = it & 1;
    const int kv0 = it * 64;

    short8 vf[4][4];
#pragma unroll
    for (int db = 0; db < 4; db++)
#pragma unroll
      for (int ks = 0; ks < 4; ks++)
        vf[db][ks] = *(const short8*)(vbase + (size_t)(db * 32 + ln) * SEQ +
                                      kv0 + ks * 16 + hi * 8);

    if (it + 1 < SEQ / 64) STAGEK(cur ^ 1, kv0 + 64);

    const char* kb = (const char*)&Ks[cur][0];
    f32x16 s0 = {}, s1 = {};
    __builtin_amdgcn_s_setprio(1);
#pragma unroll
    for (int sl = 0; sl < 8; sl++) {
      const int cw = (sl * 32 + hi * 16) ^ ((ln & 7) << 4);
      short8 kf0 = *(const short8*)(kb + ln * 256 + cw);
      short8 kf1 = *(const short8*)(kb + (32 + ln) * 256 + cw);
      s0 = mfma32(kf0, qf[sl], s0);
      s1 = mfma32(kf1, qf[sl], s1);
    }
    __builtin_amdgcn_s_setprio(0);

    float mx = s0[0];
#pragma unroll
    for (int r = 1; r < 16; r++) mx = fmaxf(mx, s0[r]);
#pragma unroll
    for (int r = 0; r < 16; r++) mx = fmaxf(mx, s1[r]);
    {
      uint2v r2 = plswap(__float_as_uint(mx), __float_as_uint(mx));
      mx = fmaxf(__uint_as_float(r2[0]), __uint_as_float(r2[1]));
    }

    if (!__all(mx <= mrow + 8.f)) {
      float mnew = fmaxf(mrow, mx);
      float fs = exp2f(mrow - mnew);
      mrow = mnew;
      lrow *= fs;
#pragma unroll
      for (int db = 0; db < 4; db++)
#pragma unroll
        for (int r = 0; r < 16; r++) oacc[db][r] *= fs;
    }

    float p0[16], p1[16];
    float sum = 0.f;
#pragma unroll
    for (int r = 0; r < 16; r++) {
      p0[r] = exp2f(s0[r] - mrow);
      sum += p0[r];
    }
#pragma unroll
    for (int r = 0; r < 16; r++) {
      p1[r] = exp2f(s1[r] - mrow);
      sum += p1[r];
    }
    lrow += sum;

    uint4v pk[4];
#define PACKSUB(P, K0)                                                       \
  {                                                                          \
    unsigned int a_, b_;                                                     \
    uint2v r_;                                                               \
    a_ = cvtpk(P[0], P[1]); b_ = cvtpk(P[4], P[5]);                          \
    r_ = plswap(a_, b_); pk[K0][0] = r_[0]; pk[K0][2] = r_[1];               \
    a_ = cvtpk(P[2], P[3]); b_ = cvtpk(P[6], P[7]);                          \
    r_ = plswap(a_, b_); pk[K0][1] = r_[0]; pk[K0][3] = r_[1];               \
    a_ = cvtpk(P[8], P[9]); b_ = cvtpk(P[12], P[13]);                        \
    r_ = plswap(a_, b_); pk[K0 + 1][0] = r_[0]; pk[K0 + 1][2] = r_[1];       \
    a_ = cvtpk(P[10], P[11]); b_ = cvtpk(P[14], P[15]);                      \
    r_ = plswap(a_, b_); pk[K0 + 1][1] = r_[0]; pk[K0 + 1][3] = r_[1];       \
  }
    PACKSUB(p0, 0);
    PACKSUB(p1, 2);
#undef PACKSUB

    __builtin_amdgcn_s_setprio(1);
#pragma unroll
    for (int db = 0; db < 4; db++)
#pragma unroll
      for (int ks = 0; ks < 4; ks++)
        oacc[db] = mfma32(vf[db][ks], __builtin_bit_cast(short8, pk[ks]),
                          oacc[db]);
    __builtin_amdgcn_s_setprio(0);

    __syncthreads();
  }
#undef STAGEK

  {
    uint2v r2 = plswap(__float_as_uint(lrow), __float_as_uint(lrow));
    lrow = __uint_as_float(r2[0]) + __uint_as_float(r2[1]);
  }
  const float inv = 1.0f / lrow;
  unsigned short* ob = o + (size_t)(b * SEQ + q0 + w * 32 + ln) * D_MODEL +
                       h * HEAD_DIM + hi * 4;
#pragma unroll
  for (int db = 0; db < 4; db++)
#pragma unroll
    for (int r = 0; r < 4; r++) {
      short4v v4;
#pragma unroll
      for (int j = 0; j < 4; j++)
        v4[j] = (short)f2b(oacc[db][4 * r + j] * inv);
      *(short4v*)(ob + db * 32 + r * 8) = v4;
    }
}

// ------- fused O-proj reduce + RMSNorm2: out = p0+p1+x+bo; h2 = rms(out) -----
__global__ __launch_bounds__(256)
void reduceo_norm_kernel(const unsigned short* __restrict__ p0,
                         const unsigned short* __restrict__ p1,
                         const float* __restrict__ bo,
                         const float* __restrict__ x,
                         const float* __restrict__ n2w,
                         float* __restrict__ out,
                         unsigned short* __restrict__ h2) {
  const int row = blockIdx.x;
  const int base = threadIdx.x * 8;
  const size_t off = (size_t)row * D_MODEL + base;
  short8 a = *(const short8*)(p0 + off);
  short8 b = *(const short8*)(p1 + off);
  float4 x0 = *(const float4*)(x + off);
  float4 x1 = *(const float4*)(x + off + 4);
  float4 bo0 = *(const float4*)(bo + base);
  float4 bo1 = *(const float4*)(bo + base + 4);
  float o[8];
  o[0] = b2f((unsigned short)a[0]) + b2f((unsigned short)b[0]) + x0.x + bo0.x;
  o[1] = b2f((unsigned short)a[1]) + b2f((unsigned short)b[1]) + x0.y + bo0.y;
  o[2] = b2f((unsigned short)a[2]) + b2f((unsigned short)b[2]) + x0.z + bo0.z;
  o[3] = b2f((unsigned short)a[3]) + b2f((unsigned short)b[3]) + x0.w + bo0.w;
  o[4] = b2f((unsigned short)a[4]) + b2f((unsigned short)b[4]) + x1.x + bo1.x;
  o[5] = b2f((unsigned short)a[5]) + b2f((unsigned short)b[5]) + x1.y + bo1.y;
  o[6] = b2f((unsigned short)a[6]) + b2f((unsigned short)b[6]) + x1.z + bo1.z;
  o[7] = b2f((unsigned short)a[7]) + b2f((unsigned short)b[7]) + x1.w + bo1.w;
  float4 w0, w1;
  w0.x = o[0]; w0.y = o[1]; w0.z = o[2]; w0.w = o[3];
  w1.x = o[4]; w1.y = o[5]; w1.z = o[6]; w1.w = o[7];
  *(float4*)(out + off) = w0;
  *(float4*)(out + off + 4) = w1;
  float ss = 0.f;
#pragma unroll
  for (int j = 0; j < 8; j++) ss += o[j] * o[j];
#pragma unroll
  for (int m = 1; m < 64; m <<= 1) ss += __shfl_xor(ss, m);
  __shared__ float red[4];
  if ((threadIdx.x & 63) == 0) red[threadIdx.x >> 6] = ss;
  __syncthreads();
  float tot = red[0] + red[1] + red[2] + red[3];
  float sc = rsqrtf(tot * (1.0f / D_MODEL) + 1e-8f);
  float4 g0 = *(const float4*)(n2w + base);
  float4 g1 = *(const float4*)(n2w + base + 4);
  short8 r;
  r[0] = f2b(o[0] * sc * g0.x); r[1] = f2b(o[1] * sc * g0.y);
  r[2] = f2b(o[2] * sc * g0.z); r[3] = f2b(o[3] * sc * g0.w);
  r[4] = f2b(o[4] * sc * g1.x); r[5] = f2b(o[5] * sc * g1.y);
  r[6] = f2b(o[6] * sc * g1.z); r[7] = f2b(o[7] * sc * g1.w);
  *(short8*)(h2 + off) = r;
}

// ---------------- split-K reduce (bf16 partials): out += p0 + p1 + b2 --------
__global__ __launch_bounds__(256)
void reduce2_kernel(const unsigned short* __restrict__ p0,
                    const unsigned short* __restrict__ p1,
                    const float* __restrict__ b2, float* __restrict__ out) {
  size_t i = (size_t)blockIdx.x * 256 + threadIdx.x;  // 8-elem chunk
  const int col8 = (int)(i & 255) * 8;
  short8 a = *(const short8*)(p0 + i * 8);
  short8 b = *(const short8*)(p1 + i * 8);
  float4 o0 = ((const float4*)out)[i * 2];
  float4 o1 = ((const float4*)out)[i * 2 + 1];
  float4 bb0 = *(const float4*)(b2 + col8);
  float4 bb1 = *(const float4*)(b2 + col8 + 4);
  o0.x += b2f((unsigned short)a[0]) + b2f((unsigned short)b[0]) + bb0.x;
  o0.y += b2f((unsigned short)a[1]) + b2f((unsigned short)b[1]) + bb0.y;
  o0.z += b2f((unsigned short)a[2]) + b2f((unsigned short)b[2]) + bb0.z;
  o0.w += b2f((unsigned short)a[3]) + b2f((unsigned short)b[3]) + bb0.w;
  o1.x += b2f((unsigned short)a[4]) + b2f((unsigned short)b[4]) + bb1.x;
  o1.y += b2f((unsigned short)a[5]) + b2f((unsigned short)b[5]) + bb1.y;
  o1.z += b2f((unsigned short)a[6]) + b2f((unsigned short)b[6]) + bb1.z;
  o1.w += b2f((unsigned short)a[7]) + b2f((unsigned short)b[7]) + bb1.w;
  ((float4*)out)[i * 2] = o0;
  ((float4*)out)[i * 2 + 1] = o1;
}

// ---------------- host: launch sequence --------------------------------------
extern "C" void kernel_launch(void* const* d_in, const int* in_sizes, int n_in,
                              void* d_out, int out_size, void* d_ws,
                              size_t ws_size, hipStream_t stream) {
  (void)in_sizes; (void)n_in; (void)out_size; (void)ws_size;
  const float* x   = (const float*)d_in[0];
  const float* Wq  = (const float*)d_in[1];
  const float* bq  = (const float*)d_in[2];
  const float* Wk  = (const float*)d_in[3];
  const float* bk  = (const float*)d_in[4];
  const float* Wv  = (const float*)d_in[5];
  const float* bv  = (const float*)d_in[6];
  const float* Wo  = (const float*)d_in[7];
  const float* bo  = (const float*)d_in[8];
  const float* rot = (const float*)d_in[9];
  const float* n1w = (const float*)d_in[10];
  const float* n2w = (const float*)d_in[11];
  const float* W1  = (const float*)d_in[12];
  const float* b1  = (const float*)d_in[13];
  const float* W2  = (const float*)d_in[14];
  const float* b2  = (const float*)d_in[15];
  float* out = (float*)d_out;
  char* ws = (char*)d_ws;

  const size_t SZ_D2  = (size_t)D_MODEL * D_MODEL * 2;   // 8 MiB
  const size_t SZ_ACT = (size_t)M_TOK * D_MODEL * 2;     // 16 MiB
  const size_t SZ_W1  = (size_t)2 * D_FF * D_MODEL * 2;  // 64 MiB
  const size_t SZ_W2  = (size_t)D_MODEL * D_FF * 2;      // 32 MiB
  const size_t SZ_G   = (size_t)M_TOK * 2 * D_FF * 2;    // 128 MiB

  size_t off = 0;
  auto alloc = [&](size_t sz) { size_t o = off; off += (sz + 255) & ~(size_t)255; return o; };
  unsigned short* wqkv_b = (unsigned short*)(ws + alloc(3 * SZ_D2));  // at ws+0
  unsigned short* wo_b   = (unsigned short*)(ws + alloc(SZ_D2));
  unsigned short* w1_b   = (unsigned short*)(ws + alloc(SZ_W1));     // permuted W1'
  unsigned short* w2_b   = (unsigned short*)(ws + alloc(SZ_W2));
  float*          biasq  = (float*)(ws + alloc(QKV_LD * 4));
  float*          b1p    = (float*)(ws + alloc(2 * D_FF * 4));
  unsigned short* h2_b   = (unsigned short*)(ws + alloc(SZ_ACT));
  char* pool = ws + alloc(SZ_G);
  // phase 1 overlay in pool: h | qkv | vt | o   (16+48+16+16 = 96 MiB)
  unsigned short* h_b   = (unsigned short*)(pool);
  unsigned short* qkv_b = (unsigned short*)(pool + SZ_ACT);
  unsigned short* vt_b  = (unsigned short*)(pool + 4 * SZ_ACT);
  unsigned short* o_b   = (unsigned short*)(pool + 5 * SZ_ACT);
  // O-proj bf16 partials overlay the then-dead h|qkv region (2 x 16 MiB)
  unsigned short* po0 = (unsigned short*)pool;
  unsigned short* po1 = po0 + (size_t)M_TOK * D_MODEL;
  // phase 2 overlay: ff (4096 x 8192 bf16 = 64 MiB) occupies pool start
  unsigned short* ff_b  = (unsigned short*)(pool);
  // W2 bf16 partials overlay the then-dead wqkv+wo region (2 x 16 MiB = 32 MiB)
  unsigned short* p0 = (unsigned short*)ws;
  unsigned short* p1 = p0 + (size_t)M_TOK * D_MODEL;

  // weights -> bf16 (merged: Wq*QSCALE | Wk | Wv -> wqkv; Wo; W2)
  cvt_all_kernel<<<2048, 256, 0, stream>>>(Wq, Wk, Wv, Wo, W2, wqkv_b, wo_b, w2_b);
  cvt_w1p_kernel<<<2048, 256, 0, stream>>>(W1, w1_b);
  biasqkv_kernel<<<QKV_LD / 256, 256, 0, stream>>>(bq, bk, bv, rot, biasq);
  permb1_kernel<<<2 * D_FF / 256, 256, 0, stream>>>(b1, b1p);

  // norm1 -> h
  rmsnorm_kernel<<<M_TOK, 256, 0, stream>>>(x, n1w, h_b);

  // fused QKV projection (2-phase 256^2, 32x32 MFMA)
  gemm_p8<0><<<dim3(QKV_LD / 256, M_TOK / 256), 512, 0, stream>>>(
      h_b, D_MODEL, wqkv_b, D_MODEL, biasq, qkv_b, QKV_LD, D_MODEL, 0);

  // V transpose + attention
  vtrans_kernel<<<dim3(SEQ / 32, BATCH * N_HEADS), 256, 0, stream>>>(qkv_b, vt_b);
  attn_kernel<<<dim3(SEQ / 256, BATCH * N_HEADS), 512, 0, stream>>>(qkv_b, vt_b, o_b);

  // O projection split-K (z=2, K=1024 each) -> bf16 partials, then fused
  // reduce + rmsnorm2 (writes out f32 + h2 bf16)
  gemm_p8<2><<<dim3(D_MODEL / 256, M_TOK / 256, 2), 512, 0, stream>>>(
      o_b, D_MODEL, wo_b, D_MODEL, nullptr, po0, D_MODEL, D_MODEL / 2,
      (size_t)M_TOK * D_MODEL);
  reduceo_norm_kernel<<<M_TOK, 256, 0, stream>>>(po0, po1, bo, x, n2w, out, h2_b);

  // W1 + fused SwiGLU -> ff (2-phase 256^2, MODE 3)
  gemm_p8<3><<<dim3(2 * D_FF / 256, M_TOK / 256), 512, 0, stream>>>(
      h2_b, D_MODEL, w1_b, D_MODEL, b1p, ff_b, 2 * D_FF, D_MODEL, 0);

  // W2 split-K (z=2) -> bf16 partials
  gemm_p8<2><<<dim3(D_MODEL / 256, M_TOK / 256, 2), 512, 0, stream>>>(
      ff_b, D_FF, w2_b, D_FF, nullptr, p0, D_MODEL, D_FF / 2,
      (size_t)M_TOK * D_MODEL);

  // out += p0 + p1 + b2
  reduce2_kernel<<<(M_TOK * D_MODEL / 8) / 256, 256, 0, stream>>>(p0, p1, b2, out);
}